// Round 1
// baseline (1304.398 us; speedup 1.0000x reference)
//
#include <hip/hip_runtime.h>
#include <math.h>

#define NNODES 50000
#define NEDGES 800000
#define DIM 256
#define HID_DIM 512

// ---------------------------------------------------------------------------
// SGEMM: C[M,Nc] = A[M,K] @ B[K,Nc] (+bias) (+exact GELU if act==1)
// 128x128 tile, BK=16, 256 threads, 8x8 per thread. fp32 (no fp32 MFMA on CDNA4).
// ---------------------------------------------------------------------------
__global__ __launch_bounds__(256) void sgemm_kernel(
    const float* __restrict__ A, const float* __restrict__ B,
    const float* __restrict__ bias, float* __restrict__ C,
    int M, int K, int Nc, int act)
{
    __shared__ float As[16][136];   // padded stride 136 floats (544B, 16B-aligned rows)
    __shared__ float Bs[16][136];

    const int nTilesN = Nc >> 7;
    const int bm = blockIdx.x / nTilesN;
    const int bn = blockIdx.x % nTilesN;
    const int m0 = bm << 7, n0 = bn << 7;
    const int t  = threadIdx.x;
    const int tx = t & 15, ty = t >> 4;

    float acc[8][8];
    #pragma unroll
    for (int i = 0; i < 8; ++i)
        #pragma unroll
        for (int j = 0; j < 8; ++j) acc[i][j] = 0.f;

    const int arow0 = t >> 2;          // 0..63
    const int ac4   = (t & 3) << 2;    // 0,4,8,12
    const int brow0 = t >> 5;          // 0..7
    const int bc    = (t & 31) << 2;   // 0..124

    for (int k0 = 0; k0 < K; k0 += 16) {
        #pragma unroll
        for (int r = 0; r < 2; ++r) {
            int ar = arow0 + r * 64;
            int gm = m0 + ar;
            float4 av = make_float4(0.f, 0.f, 0.f, 0.f);
            if (gm < M) av = *(const float4*)(A + (size_t)gm * K + k0 + ac4);
            As[ac4 + 0][ar] = av.x;
            As[ac4 + 1][ar] = av.y;
            As[ac4 + 2][ar] = av.z;
            As[ac4 + 3][ar] = av.w;

            int br = brow0 + r * 8;
            float4 bv = *(const float4*)(B + (size_t)(k0 + br) * Nc + n0 + bc);
            *(float4*)&Bs[br][bc] = bv;
        }
        __syncthreads();
        #pragma unroll
        for (int k = 0; k < 16; ++k) {
            float4 a0 = *(const float4*)&As[k][ty * 8];
            float4 a1 = *(const float4*)&As[k][ty * 8 + 4];
            float4 b0 = *(const float4*)&Bs[k][tx * 8];
            float4 b1 = *(const float4*)&Bs[k][tx * 8 + 4];
            float ar_[8] = {a0.x, a0.y, a0.z, a0.w, a1.x, a1.y, a1.z, a1.w};
            float br_[8] = {b0.x, b0.y, b0.z, b0.w, b1.x, b1.y, b1.z, b1.w};
            #pragma unroll
            for (int i = 0; i < 8; ++i)
                #pragma unroll
                for (int j = 0; j < 8; ++j)
                    acc[i][j] += ar_[i] * br_[j];
        }
        __syncthreads();
    }

    float bv[8];
    #pragma unroll
    for (int j = 0; j < 8; ++j) bv[j] = bias ? bias[n0 + tx * 8 + j] : 0.f;

    #pragma unroll
    for (int i = 0; i < 8; ++i) {
        int row = m0 + ty * 8 + i;
        if (row >= M) continue;
        float o[8];
        #pragma unroll
        for (int j = 0; j < 8; ++j) {
            float v = acc[i][j] + bv[j];
            if (act == 1) v = 0.5f * v * (1.f + erff(v * 0.70710678118654752f));
            o[j] = v;
        }
        *(float4*)(C + (size_t)row * Nc + n0 + tx * 8)     = make_float4(o[0], o[1], o[2], o[3]);
        *(float4*)(C + (size_t)row * Nc + n0 + tx * 8 + 4) = make_float4(o[4], o[5], o[6], o[7]);
    }
}

// ---------------------------------------------------------------------------
// CSR build: histogram by dst, 3-phase exclusive scan, atomic-cursor scatter.
// ---------------------------------------------------------------------------
__global__ void hist_kernel(const int* __restrict__ dst, int* __restrict__ counts, int E)
{
    int e = blockIdx.x * blockDim.x + threadIdx.x;
    if (e < E) atomicAdd(&counts[dst[e]], 1);
}

__global__ void scan1_kernel(const int* __restrict__ counts, int* __restrict__ starts,
                             int* __restrict__ bsums, int N)
{
    __shared__ int tmp[256];
    int t = threadIdx.x;
    int i = blockIdx.x * 256 + t;
    int v = (i < N) ? counts[i] : 0;
    tmp[t] = v;
    __syncthreads();
    for (int off = 1; off < 256; off <<= 1) {
        int add = (t >= off) ? tmp[t - off] : 0;
        __syncthreads();
        tmp[t] += add;
        __syncthreads();
    }
    if (i < N) starts[i] = tmp[t] - v;      // block-local exclusive
    if (t == 255) bsums[blockIdx.x] = tmp[255];
}

__global__ void scan2_kernel(const int* __restrict__ bsums, int* __restrict__ bexc, int NB)
{
    __shared__ int tmp[256];
    int t = threadIdx.x;
    int v = (t < NB) ? bsums[t] : 0;
    tmp[t] = v;
    __syncthreads();
    for (int off = 1; off < 256; off <<= 1) {
        int add = (t >= off) ? tmp[t - off] : 0;
        __syncthreads();
        tmp[t] += add;
        __syncthreads();
    }
    bexc[t] = tmp[t] - v;
}

__global__ void scan3_kernel(int* __restrict__ starts, const int* __restrict__ bexc,
                             const int* __restrict__ counts, int N)
{
    int t = threadIdx.x;
    int i = blockIdx.x * 256 + t;
    if (i < N) {
        int val = starts[i] + bexc[blockIdx.x];
        starts[i] = val;
        if (i == N - 1) starts[N] = val + counts[i];
    }
}

__global__ void scatter_kernel(const int* __restrict__ src, const int* __restrict__ dst,
                               int* __restrict__ cursor, int* __restrict__ csr_src, int E)
{
    int e = blockIdx.x * blockDim.x + threadIdx.x;
    if (e < E) {
        int d = dst[e];
        int slot = atomicAdd(&cursor[d], 1);
        csr_src[slot] = src[e];
    }
}

// ---------------------------------------------------------------------------
// Attention: one block (256 thr) per dst node; thread t = channel t, head = t>>5.
// Online softmax with m init 0 (matches include_self=True max on zeros buffer),
// l sums only edge terms; out = acc / (l + 1e-8).
// ---------------------------------------------------------------------------
__global__ __launch_bounds__(256) void attn_kernel(
    const float* __restrict__ Q, const float* __restrict__ K, const float* __restrict__ V,
    const int* __restrict__ starts, const int* __restrict__ csr_src,
    float* __restrict__ out)
{
    const int n = blockIdx.x;
    const int c = threadIdx.x;
    const float q = Q[(size_t)n * DIM + c];
    const int beg = starts[n], end = starts[n + 1];
    float m = 0.f, l = 0.f, acc = 0.f;
    for (int e = beg; e < end; ++e) {
        int s = csr_src[e];
        float kv = K[(size_t)s * DIM + c];
        float d = q * kv;
        d += __shfl_xor(d, 1, 32);
        d += __shfl_xor(d, 2, 32);
        d += __shfl_xor(d, 4, 32);
        d += __shfl_xor(d, 8, 32);
        d += __shfl_xor(d, 16, 32);
        float sc = d * 0.17677669529663688f;   // D^-0.5, D=32
        float vv = V[(size_t)s * DIM + c];
        float mn = fmaxf(m, sc);
        float p  = __expf(sc - mn);
        float al = __expf(m - mn);
        l   = l * al + p;
        acc = acc * al + p * vv;
        m = mn;
    }
    out[(size_t)n * DIM + c] = acc / (l + 1e-8f);
}

// ---------------------------------------------------------------------------
// LayerNorm(a + b) * g + beta, one block per row (DIM=256 channels).
// ---------------------------------------------------------------------------
__global__ __launch_bounds__(256) void ln_kernel(
    const float* __restrict__ a, const float* __restrict__ b,
    const float* __restrict__ g, const float* __restrict__ beta,
    float* __restrict__ out)
{
    const int n = blockIdx.x;
    const int t = threadIdx.x;
    float x = a[(size_t)n * DIM + t] + b[(size_t)n * DIM + t];
    float s = x, s2 = x * x;
    #pragma unroll
    for (int off = 32; off >= 1; off >>= 1) {
        s  += __shfl_xor(s,  off, 64);
        s2 += __shfl_xor(s2, off, 64);
    }
    __shared__ float sb[4], sb2[4];
    int w = t >> 6;
    if ((t & 63) == 0) { sb[w] = s; sb2[w] = s2; }
    __syncthreads();
    float tot  = sb[0] + sb[1] + sb[2] + sb[3];
    float tot2 = sb2[0] + sb2[1] + sb2[2] + sb2[3];
    float mean = tot * (1.f / DIM);
    float var  = tot2 * (1.f / DIM) - mean * mean;
    float inv  = rsqrtf(var + 1e-5f);
    out[(size_t)n * DIM + t] = (x - mean) * inv * g[t] + beta[t];
}

// ---------------------------------------------------------------------------
extern "C" void kernel_launch(void* const* d_in, const int* in_sizes, int n_in,
                              void* d_out, int out_size, void* d_ws, size_t ws_size,
                              hipStream_t stream)
{
    const float* x     = (const float*)d_in[0];
    const int*   edge  = (const int*)d_in[1];   // [2,E]: row0=src, row1=dst (harness passes ints as int32)
    const float* Wq    = (const float*)d_in[3];
    const float* Wk    = (const float*)d_in[4];
    const float* Wv    = (const float*)d_in[5];
    const float* Wo_w  = (const float*)d_in[6];
    const float* Wo_b  = (const float*)d_in[7];
    const float* ln1_g = (const float*)d_in[8];
    const float* ln1_b = (const float*)d_in[9];
    const float* ln2_g = (const float*)d_in[10];
    const float* ln2_b = (const float*)d_in[11];
    const float* fw1   = (const float*)d_in[12];
    const float* fb1   = (const float*)d_in[13];
    const float* fw2   = (const float*)d_in[14];
    const float* fb2   = (const float*)d_in[15];
    const int* srcA = edge;
    const int* dstA = edge + NEDGES;

    char* wsb = (char*)d_ws;
    const size_t SZ = (size_t)NNODES * DIM * sizeof(float);   // 51.2 MB
    float* Qb  = (float*)(wsb);
    float* Kb  = (float*)(wsb + SZ);
    float* Vb  = (float*)(wsb + 2 * SZ);
    float* AO  = (float*)(wsb + 3 * SZ);
    float* WO  = Qb;   // Q dead after attention
    float* O1  = Kb;   // K dead after attention
    float* HID = Vb;   // V+AO dead after Wo GEMM; spans [2SZ,4SZ)
    float* FF  = Qb;   // WO dead after LN1
    char* ip = wsb + 4 * SZ;
    int* counts = (int*)ip;  ip += sizeof(int) * NNODES;
    int* starts = (int*)ip;  ip += sizeof(int) * (NNODES + 1);
    int* bsums  = (int*)ip;  ip += sizeof(int) * 256;
    int* bexc   = (int*)ip;  ip += sizeof(int) * 256;
    int* cursor = (int*)ip;  ip += sizeof(int) * NNODES;
    int* csr    = (int*)ip;  ip += sizeof(int) * NEDGES;

    const int NB = (NNODES + 255) / 256;       // 196
    const int gT = (NNODES + 127) / 128;       // 391 row tiles
    dim3 blk(256);

    // QKV projections
    sgemm_kernel<<<gT * 2, blk, 0, stream>>>(x, Wq, nullptr, Qb, NNODES, DIM, DIM, 0);
    sgemm_kernel<<<gT * 2, blk, 0, stream>>>(x, Wk, nullptr, Kb, NNODES, DIM, DIM, 0);
    sgemm_kernel<<<gT * 2, blk, 0, stream>>>(x, Wv, nullptr, Vb, NNODES, DIM, DIM, 0);

    // CSR by dst
    hipMemsetAsync(counts, 0, sizeof(int) * NNODES, stream);
    hist_kernel<<<(NEDGES + 255) / 256, blk, 0, stream>>>(dstA, counts, NEDGES);
    scan1_kernel<<<NB, blk, 0, stream>>>(counts, starts, bsums, NNODES);
    scan2_kernel<<<1, blk, 0, stream>>>(bsums, bexc, NB);
    scan3_kernel<<<NB, blk, 0, stream>>>(starts, bexc, counts, NNODES);
    hipMemcpyAsync(cursor, starts, sizeof(int) * NNODES, hipMemcpyDeviceToDevice, stream);
    scatter_kernel<<<(NEDGES + 255) / 256, blk, 0, stream>>>(srcA, dstA, cursor, csr, NEDGES);

    // Segmented attention
    attn_kernel<<<NNODES, blk, 0, stream>>>(Qb, Kb, Vb, starts, csr, AO);

    // Output projection + LN1
    sgemm_kernel<<<gT * 2, blk, 0, stream>>>(AO, Wo_w, Wo_b, WO, NNODES, DIM, DIM, 0);
    ln_kernel<<<NNODES, blk, 0, stream>>>(x, WO, ln1_g, ln1_b, O1);

    // FFN + LN2
    sgemm_kernel<<<gT * 4, blk, 0, stream>>>(O1, fw1, fb1, HID, NNODES, DIM, HID_DIM, 1);
    sgemm_kernel<<<gT * 2, blk, 0, stream>>>(HID, fw2, fb2, FF, NNODES, HID_DIM, DIM, 0);
    ln_kernel<<<NNODES, blk, 0, stream>>>(O1, FF, ln2_g, ln2_b, (float*)d_out);
}

// Round 2
// 709.243 us; speedup vs baseline: 1.8391x; 1.8391x over previous
//
#include <hip/hip_runtime.h>
#include <hip/hip_bf16.h>
#include <math.h>

#define NNODES 50000
#define NEDGES 800000
#define DIM 256
#define HID_DIM 512

typedef short bf16x8 __attribute__((ext_vector_type(8)));   // 8 bf16 in 4 VGPRs
typedef float f32x4 __attribute__((ext_vector_type(4)));

__device__ __forceinline__ float to_f(float v) { return v; }
__device__ __forceinline__ float to_f(__hip_bfloat16 v) { return __bfloat162float(v); }

// ---------------------------------------------------------------------------
// bf16 MFMA GEMM: C[M,Nc](bf16) = A[M,K](bf16) @ BT[Nc,K]^T (+bias) (+GELU)
// 128x128 tile, BK=32, 256 threads = 4 waves, each wave a 64x64 quadrant
// (4x4 tiles of 16x16x32 MFMA). LDS rows padded +8 bf16 -> 2-way bank alias (free).
// ---------------------------------------------------------------------------
__global__ __launch_bounds__(256) void gemm_bf16_kernel(
    const __hip_bfloat16* __restrict__ A,    // [M][K]
    const __hip_bfloat16* __restrict__ BT,   // [Nc][K]  (pre-transposed weight)
    const float* __restrict__ bias,          // [Nc] or null
    __hip_bfloat16* __restrict__ C,          // [M][Nc]
    int M, int K, int Nc, int act)
{
    constexpr int LDA = 40;                  // 32 + 8 pad (bf16 elems) = 80 B rows
    __shared__ __align__(16) short As[128 * LDA];
    __shared__ __align__(16) short Bs[128 * LDA];

    const int nTilesN = Nc >> 7;
    const int bm = blockIdx.x / nTilesN;
    const int bn = blockIdx.x % nTilesN;
    const int m0 = bm << 7, n0 = bn << 7;
    const int t = threadIdx.x;
    const int wave = t >> 6, lane = t & 63;
    const int quad = lane >> 4, l16 = lane & 15;
    const int wm = (wave & 1) << 6, wn = (wave >> 1) << 6;

    f32x4 acc[4][4] = {};

    // staging: 512 x 16B chunks per tile, 2 per thread per matrix
    const int r0 = t >> 2;                   // 0..63
    const int kc = (t & 3) << 3;             // 0,8,16,24 (bf16 elems)

    for (int k0 = 0; k0 < K; k0 += 32) {
        #pragma unroll
        for (int h = 0; h < 2; ++h) {
            int row = r0 + h * 64;
            int gm = m0 + row;
            uint4 av = make_uint4(0u, 0u, 0u, 0u);
            if (gm < M) av = *(const uint4*)(A + (size_t)gm * K + k0 + kc);
            *(uint4*)(&As[row * LDA + kc]) = av;
            int gn = n0 + row;               // always < Nc (Nc % 128 == 0)
            uint4 bv = *(const uint4*)(BT + (size_t)gn * K + k0 + kc);
            *(uint4*)(&Bs[row * LDA + kc]) = bv;
        }
        __syncthreads();
        bf16x8 af[4], bfr[4];
        #pragma unroll
        for (int i = 0; i < 4; ++i)
            af[i] = *(const bf16x8*)(&As[(wm + i * 16 + l16) * LDA + quad * 8]);
        #pragma unroll
        for (int j = 0; j < 4; ++j)
            bfr[j] = *(const bf16x8*)(&Bs[(wn + j * 16 + l16) * LDA + quad * 8]);
        #pragma unroll
        for (int i = 0; i < 4; ++i)
            #pragma unroll
            for (int j = 0; j < 4; ++j)
                acc[i][j] = __builtin_amdgcn_mfma_f32_16x16x32_bf16(af[i], bfr[j], acc[i][j], 0, 0, 0);
        __syncthreads();
    }

    // C/D layout: col = lane&15, row = quad*4 + reg
    #pragma unroll
    for (int i = 0; i < 4; ++i) {
        int rbase = m0 + wm + i * 16 + quad * 4;
        #pragma unroll
        for (int r = 0; r < 4; ++r) {
            int row = rbase + r;
            if (row >= M) continue;
            #pragma unroll
            for (int j = 0; j < 4; ++j) {
                int col = n0 + wn + j * 16 + l16;
                float v = acc[i][j][r];
                if (bias) v += bias[col];
                if (act) v = 0.5f * v * (1.f + erff(v * 0.70710678118654752f));
                C[(size_t)row * Nc + col] = __float2bfloat16(v);
            }
        }
    }
}

// ---------------------------------------------------------------------------
// fp32 -> bf16 (4 elems/thread)
// ---------------------------------------------------------------------------
__global__ void conv_bf16_kernel(const float* __restrict__ in,
                                 __hip_bfloat16* __restrict__ out, int n4)
{
    int i = blockIdx.x * 256 + threadIdx.x;
    if (i < n4) {
        float4 v = ((const float4*)in)[i];
        __hip_bfloat162 p0, p1;
        p0.x = __float2bfloat16(v.x); p0.y = __float2bfloat16(v.y);
        p1.x = __float2bfloat16(v.z); p1.y = __float2bfloat16(v.w);
        ((__hip_bfloat162*)out)[i * 2]     = p0;
        ((__hip_bfloat162*)out)[i * 2 + 1] = p1;
    }
}

// W[K][N] fp32 -> WT[N][K] bf16
__global__ void transpose_bf16_kernel(const float* __restrict__ W,
                                      __hip_bfloat16* __restrict__ WT, int K, int N)
{
    int idx = blockIdx.x * 256 + threadIdx.x;
    if (idx < K * N) {
        int k = idx / N, n = idx % N;
        WT[(size_t)n * K + k] = __float2bfloat16(W[idx]);
    }
}

// ---------------------------------------------------------------------------
// CSR build
// ---------------------------------------------------------------------------
__global__ void hist_kernel(const int* __restrict__ dst, int* __restrict__ counts, int E)
{
    int e = blockIdx.x * blockDim.x + threadIdx.x;
    if (e < E) atomicAdd(&counts[dst[e]], 1);
}

__global__ void scan1_kernel(const int* __restrict__ counts, int* __restrict__ starts,
                             int* __restrict__ bsums, int N)
{
    __shared__ int tmp[256];
    int t = threadIdx.x;
    int i = blockIdx.x * 256 + t;
    int v = (i < N) ? counts[i] : 0;
    tmp[t] = v;
    __syncthreads();
    for (int off = 1; off < 256; off <<= 1) {
        int add = (t >= off) ? tmp[t - off] : 0;
        __syncthreads();
        tmp[t] += add;
        __syncthreads();
    }
    if (i < N) starts[i] = tmp[t] - v;
    if (t == 255) bsums[blockIdx.x] = tmp[255];
}

__global__ void scan2_kernel(const int* __restrict__ bsums, int* __restrict__ bexc, int NB)
{
    __shared__ int tmp[256];
    int t = threadIdx.x;
    int v = (t < NB) ? bsums[t] : 0;
    tmp[t] = v;
    __syncthreads();
    for (int off = 1; off < 256; off <<= 1) {
        int add = (t >= off) ? tmp[t - off] : 0;
        __syncthreads();
        tmp[t] += add;
        __syncthreads();
    }
    bexc[t] = tmp[t] - v;
}

__global__ void scan3_kernel(int* __restrict__ starts, const int* __restrict__ bexc,
                             const int* __restrict__ counts, int N)
{
    int t = threadIdx.x;
    int i = blockIdx.x * 256 + t;
    if (i < N) {
        int val = starts[i] + bexc[blockIdx.x];
        starts[i] = val;
        if (i == N - 1) starts[N] = val + counts[i];
    }
}

__global__ void scatter_kernel(const int* __restrict__ src, const int* __restrict__ dst,
                               int* __restrict__ cursor, int* __restrict__ csr_src, int E)
{
    int e = blockIdx.x * blockDim.x + threadIdx.x;
    if (e < E) {
        int d = dst[e];
        int slot = atomicAdd(&cursor[d], 1);
        csr_src[slot] = src[e];
    }
}

// ---------------------------------------------------------------------------
// Attention over bf16 QKV packed [M][768] (Q:0-255, K:256-511, V:512-767).
// 2 nodes/block (256 thr); 128 threads per node, 2 channels/thread.
// Online softmax, m init 0 (matches include_self=True amax on zeros buffer).
// ---------------------------------------------------------------------------
__global__ __launch_bounds__(256) void attn_kernel(
    const __hip_bfloat16* __restrict__ QKV,
    const int* __restrict__ starts, const int* __restrict__ csr_src,
    __hip_bfloat16* __restrict__ out)   // [M][256]
{
    const int n = blockIdx.x * 2 + (threadIdx.x >> 7);
    const int t = threadIdx.x & 127;   // channel-pair id
    const int c = t * 2;
    const size_t qb = (size_t)n * 768;
    float q0 = __bfloat162float(QKV[qb + c]);
    float q1 = __bfloat162float(QKV[qb + c + 1]);
    const int beg = starts[n], end = starts[n + 1];
    float m = 0.f, l = 0.f, a0 = 0.f, a1 = 0.f;
    for (int e = beg; e < end; ++e) {
        int s = csr_src[e];
        const size_t sb = (size_t)s * 768;
        __hip_bfloat162 kv = *(const __hip_bfloat162*)(QKV + sb + 256 + c);
        __hip_bfloat162 vv = *(const __hip_bfloat162*)(QKV + sb + 512 + c);
        float d = q0 * __bfloat162float(kv.x) + q1 * __bfloat162float(kv.y);
        d += __shfl_xor(d, 1, 16);
        d += __shfl_xor(d, 2, 16);
        d += __shfl_xor(d, 4, 16);
        d += __shfl_xor(d, 8, 16);
        float sc = d * 0.17677669529663688f;     // D^-0.5, D=32
        float v0 = __bfloat162float(vv.x);
        float v1 = __bfloat162float(vv.y);
        float mn = fmaxf(m, sc);
        float p  = __expf(sc - mn);
        float al = __expf(m - mn);
        l  = l  * al + p;
        a0 = a0 * al + p * v0;
        a1 = a1 * al + p * v1;
        m = mn;
    }
    float inv = 1.f / (l + 1e-8f);
    __hip_bfloat162 o;
    o.x = __float2bfloat16(a0 * inv);
    o.y = __float2bfloat16(a1 * inv);
    *(__hip_bfloat162*)(out + (size_t)n * DIM + c) = o;
}

// ---------------------------------------------------------------------------
// LayerNorm(a + b) * g + beta; mixed input types; fp32 and/or bf16 output.
// ---------------------------------------------------------------------------
template <typename TA, typename TB>
__global__ __launch_bounds__(256) void ln_kernel(
    const TA* __restrict__ a, const TB* __restrict__ b,
    const float* __restrict__ g, const float* __restrict__ beta,
    float* __restrict__ outf, __hip_bfloat16* __restrict__ outh)
{
    const int n = blockIdx.x;
    const int t = threadIdx.x;
    float x = to_f(a[(size_t)n * DIM + t]) + to_f(b[(size_t)n * DIM + t]);
    float s = x, s2 = x * x;
    #pragma unroll
    for (int off = 32; off >= 1; off >>= 1) {
        s  += __shfl_xor(s,  off, 64);
        s2 += __shfl_xor(s2, off, 64);
    }
    __shared__ float sb[4], sb2[4];
    int w = t >> 6;
    if ((t & 63) == 0) { sb[w] = s; sb2[w] = s2; }
    __syncthreads();
    float tot  = sb[0] + sb[1] + sb[2] + sb[3];
    float tot2 = sb2[0] + sb2[1] + sb2[2] + sb2[3];
    float mean = tot * (1.f / DIM);
    float var  = tot2 * (1.f / DIM) - mean * mean;
    float inv  = rsqrtf(var + 1e-5f);
    float o = (x - mean) * inv * g[t] + beta[t];
    if (outf) outf[(size_t)n * DIM + t] = o;
    if (outh) outh[(size_t)n * DIM + t] = __float2bfloat16(o);
}

// ---------------------------------------------------------------------------
extern "C" void kernel_launch(void* const* d_in, const int* in_sizes, int n_in,
                              void* d_out, int out_size, void* d_ws, size_t ws_size,
                              hipStream_t stream)
{
    const float* x     = (const float*)d_in[0];
    const int*   edge  = (const int*)d_in[1];
    const float* Wq    = (const float*)d_in[3];
    const float* Wk    = (const float*)d_in[4];
    const float* Wv    = (const float*)d_in[5];
    const float* Wo_w  = (const float*)d_in[6];
    const float* Wo_b  = (const float*)d_in[7];
    const float* ln1_g = (const float*)d_in[8];
    const float* ln1_b = (const float*)d_in[9];
    const float* ln2_g = (const float*)d_in[10];
    const float* ln2_b = (const float*)d_in[11];
    const float* fw1   = (const float*)d_in[12];
    const float* fb1   = (const float*)d_in[13];
    const float* fw2   = (const float*)d_in[14];
    const float* fb2   = (const float*)d_in[15];
    const int* srcA = edge;
    const int* dstA = edge + NEDGES;

    char* p = (char*)d_ws;
    const size_t QKV_SZ = (size_t)NNODES * 768 * 2;   // 76.8 MB
    const size_t H_SZ   = (size_t)NNODES * DIM * 2;   // 25.6 MB
    const size_t HID_SZ = (size_t)NNODES * HID_DIM * 2; // 51.2 MB
    __hip_bfloat16* QKVh = (__hip_bfloat16*)p;  p += QKV_SZ;
    __hip_bfloat16* AOh  = (__hip_bfloat16*)p;  p += H_SZ;
    __hip_bfloat16* O1h  = (__hip_bfloat16*)p;  p += H_SZ;
    __hip_bfloat16* HIDh = (__hip_bfloat16*)p;  p += HID_SZ;
    __hip_bfloat16* xh   = (__hip_bfloat16*)p;  p += H_SZ;
    // dead-region reuse inside QKVh (QKV dead after attention):
    __hip_bfloat16* WOh  = QKVh;                          // 25.6 MB
    __hip_bfloat16* FFh  = QKVh + (size_t)NNODES * DIM;   // next 25.6 MB
    // bf16 transposed weights
    __hip_bfloat16* WqkvT = (__hip_bfloat16*)p; p += (size_t)768 * 256 * 2;
    __hip_bfloat16* WoT   = (__hip_bfloat16*)p; p += (size_t)256 * 256 * 2;
    __hip_bfloat16* fw1T  = (__hip_bfloat16*)p; p += (size_t)512 * 256 * 2;
    __hip_bfloat16* fw2T  = (__hip_bfloat16*)p; p += (size_t)256 * 512 * 2;
    int* counts = (int*)p;  p += sizeof(int) * NNODES;
    int* starts = (int*)p;  p += sizeof(int) * (NNODES + 1);
    int* bsums  = (int*)p;  p += sizeof(int) * 256;
    int* bexc   = (int*)p;  p += sizeof(int) * 256;
    int* cursor = (int*)p;  p += sizeof(int) * NNODES;
    int* csr    = (int*)p;  p += sizeof(int) * NEDGES;

    const int NB = (NNODES + 255) / 256;
    const int mT = (NNODES + 127) / 128;      // 391
    dim3 blk(256);

    // input conversions
    conv_bf16_kernel<<<(NNODES * DIM / 4 + 255) / 256, blk, 0, stream>>>(x, xh, NNODES * DIM / 4);
    transpose_bf16_kernel<<<256, blk, 0, stream>>>(Wq, WqkvT,             256, 256);
    transpose_bf16_kernel<<<256, blk, 0, stream>>>(Wk, WqkvT + 256 * 256, 256, 256);
    transpose_bf16_kernel<<<256, blk, 0, stream>>>(Wv, WqkvT + 512 * 256, 256, 256);
    transpose_bf16_kernel<<<256, blk, 0, stream>>>(Wo_w, WoT, 256, 256);
    transpose_bf16_kernel<<<512, blk, 0, stream>>>(fw1, fw1T, 256, 512);
    transpose_bf16_kernel<<<512, blk, 0, stream>>>(fw2, fw2T, 512, 256);

    // CSR by dst
    hipMemsetAsync(counts, 0, sizeof(int) * NNODES, stream);
    hist_kernel<<<(NEDGES + 255) / 256, blk, 0, stream>>>(dstA, counts, NEDGES);
    scan1_kernel<<<NB, blk, 0, stream>>>(counts, starts, bsums, NNODES);
    scan2_kernel<<<1, blk, 0, stream>>>(bsums, bexc, NB);
    scan3_kernel<<<NB, blk, 0, stream>>>(starts, bexc, counts, NNODES);
    hipMemcpyAsync(cursor, starts, sizeof(int) * NNODES, hipMemcpyDeviceToDevice, stream);
    scatter_kernel<<<(NEDGES + 255) / 256, blk, 0, stream>>>(srcA, dstA, cursor, csr, NEDGES);

    // fused QKV projection: [M,256] @ [256,768]
    gemm_bf16_kernel<<<mT * 6, blk, 0, stream>>>(xh, WqkvT, nullptr, QKVh, NNODES, 256, 768, 0);

    // segmented attention
    attn_kernel<<<NNODES / 2, blk, 0, stream>>>(QKVh, starts, csr, AOh);

    // output projection + LN1
    gemm_bf16_kernel<<<mT * 2, blk, 0, stream>>>(AOh, WoT, Wo_b, WOh, NNODES, 256, 256, 0);
    ln_kernel<float, __hip_bfloat16><<<NNODES, blk, 0, stream>>>(x, WOh, ln1_g, ln1_b, nullptr, O1h);

    // FFN + LN2
    gemm_bf16_kernel<<<mT * 4, blk, 0, stream>>>(O1h, fw1T, fb1, HIDh, NNODES, 256, 512, 1);
    gemm_bf16_kernel<<<mT * 2, blk, 0, stream>>>(HIDh, fw2T, fb2, FFh, NNODES, 512, 256, 0);
    ln_kernel<__hip_bfloat16, __hip_bfloat16><<<NNODES, blk, 0, stream>>>(O1h, FFh, ln2_g, ln2_b, (float*)d_out, nullptr);
}

// Round 4
// 605.079 us; speedup vs baseline: 2.1557x; 1.1721x over previous
//
#include <hip/hip_runtime.h>
#include <hip/hip_bf16.h>
#include <math.h>

#define NNODES 50000
#define NEDGES 800000
#define DIM 256
#define HID_DIM 512

typedef short bf16x8 __attribute__((ext_vector_type(8)));
typedef float f32x4 __attribute__((ext_vector_type(4)));

__device__ __forceinline__ float to_f(float v) { return v; }
__device__ __forceinline__ float to_f(__hip_bfloat16 v) { return __bfloat162float(v); }
__device__ __forceinline__ float bf2f(unsigned short u) {
    return __uint_as_float(((unsigned)u) << 16);
}
__device__ __forceinline__ unsigned short f2bf_u16(float v) {
    __hip_bfloat16 h = __float2bfloat16(v);
    return __builtin_bit_cast(unsigned short, h);
}

// async global->LDS, 16B per lane; LDS dest = wave-uniform base + lane*16
#define GLD(g, l) __builtin_amdgcn_global_load_lds( \
    (const __attribute__((address_space(1))) unsigned int*)(g), \
    (__attribute__((address_space(3))) unsigned int*)(l), 16, 0, 0)

// ---------------------------------------------------------------------------
// bf16 MFMA GEMM: C[M,Nc](bf16) = A[M,K](bf16) @ BT[Nc,K]^T (+bias) (+GELU)
// 128x128 tile, BK=32, 4 waves, global_load_lds staging (m97 structure).
// LDS unpadded [128][32] (global_load_lds requires contiguous lane order).
// ---------------------------------------------------------------------------
__global__ __launch_bounds__(256) void gemm_bf16_kernel(
    const __hip_bfloat16* __restrict__ A,    // [M][K]
    const __hip_bfloat16* __restrict__ BT,   // [Nc][K]
    const float* __restrict__ bias,
    __hip_bfloat16* __restrict__ C,          // [M][Nc]
    int M, int K, int Nc, int act)
{
    __shared__ __align__(16) short As[128 * 32];
    __shared__ __align__(16) short Bs[128 * 32];

    const int nTilesN = Nc >> 7;
    const int bm = blockIdx.x / nTilesN;
    const int bn = blockIdx.x % nTilesN;
    const int m0 = bm << 7, n0 = bn << 7;
    const int t = threadIdx.x;
    const int wave = t >> 6, lane = t & 63;
    const int quad = lane >> 4, l16 = lane & 15;
    const int wm = (wave & 1) << 6, wn = (wave >> 1) << 6;

    f32x4 acc[4][4] = {};

    // chunk id (16B units): 4 chunks per 32-elem row
    const int chunk = wave * 64 + lane;            // 0..255
    const int row = chunk >> 2;                    // 0..63
    const int kc = (chunk & 3) << 3;               // 0,8,16,24
    int gmA0 = m0 + row;       if (gmA0 >= M) gmA0 = M - 1;
    int gmA1 = m0 + row + 64;  if (gmA1 >= M) gmA1 = M - 1;
    const size_t aoff0 = (size_t)gmA0 * K + kc;
    const size_t aoff1 = (size_t)gmA1 * K + kc;
    const size_t boff0 = (size_t)(n0 + row) * K + kc;
    const size_t boff1 = (size_t)(n0 + row + 64) * K + kc;
    short* ldsA0 = &As[(wave * 64) * 8];           // wave-uniform bases
    short* ldsA1 = &As[(256 + wave * 64) * 8];
    short* ldsB0 = &Bs[(wave * 64) * 8];
    short* ldsB1 = &Bs[(256 + wave * 64) * 8];

    for (int k0 = 0; k0 < K; k0 += 32) {
        GLD(A + aoff0 + k0, ldsA0);
        GLD(A + aoff1 + k0, ldsA1);
        GLD(BT + boff0 + k0, ldsB0);
        GLD(BT + boff1 + k0, ldsB1);
        __syncthreads();
        bf16x8 af[4], bfr[4];
        #pragma unroll
        for (int i = 0; i < 4; ++i)
            af[i] = *(const bf16x8*)(&As[(wm + i * 16 + l16) * 32 + quad * 8]);
        #pragma unroll
        for (int j = 0; j < 4; ++j)
            bfr[j] = *(const bf16x8*)(&Bs[(wn + j * 16 + l16) * 32 + quad * 8]);
        #pragma unroll
        for (int i = 0; i < 4; ++i)
            #pragma unroll
            for (int j = 0; j < 4; ++j)
                acc[i][j] = __builtin_amdgcn_mfma_f32_16x16x32_bf16(af[i], bfr[j], acc[i][j], 0, 0, 0);
        __syncthreads();
    }

    // C/D layout: col = lane&15, row = quad*4 + reg
    #pragma unroll
    for (int i = 0; i < 4; ++i) {
        int rbase = m0 + wm + i * 16 + quad * 4;
        #pragma unroll
        for (int r = 0; r < 4; ++r) {
            int rowg = rbase + r;
            if (rowg >= M) continue;
            #pragma unroll
            for (int j = 0; j < 4; ++j) {
                int col = n0 + wn + j * 16 + l16;
                float v = acc[i][j][r];
                if (bias) v += bias[col];
                if (act) v = 0.5f * v * (1.f + erff(v * 0.70710678118654752f));
                C[(size_t)rowg * Nc + col] = __float2bfloat16(v);
            }
        }
    }
}

// ---------------------------------------------------------------------------
// fp32 -> bf16 (4 elems/thread)
// ---------------------------------------------------------------------------
__global__ void conv_bf16_kernel(const float* __restrict__ in,
                                 __hip_bfloat16* __restrict__ out, int n4)
{
    int i = blockIdx.x * 256 + threadIdx.x;
    if (i < n4) {
        float4 v = ((const float4*)in)[i];
        __hip_bfloat162 p0, p1;
        p0.x = __float2bfloat16(v.x); p0.y = __float2bfloat16(v.y);
        p1.x = __float2bfloat16(v.z); p1.y = __float2bfloat16(v.w);
        ((__hip_bfloat162*)out)[i * 2]     = p0;
        ((__hip_bfloat162*)out)[i * 2 + 1] = p1;
    }
}

// all weight transposes fused: W[K][N] fp32 -> WT[N][K] bf16 (grid = 2048 blocks)
__global__ void prep_w_kernel(const float* __restrict__ Wq, const float* __restrict__ Wk,
                              const float* __restrict__ Wv, const float* __restrict__ Wo,
                              const float* __restrict__ f1, const float* __restrict__ f2,
                              __hip_bfloat16* __restrict__ WqkvT, __hip_bfloat16* __restrict__ WoT,
                              __hip_bfloat16* __restrict__ f1T, __hip_bfloat16* __restrict__ f2T)
{
    int b = blockIdx.x, t = threadIdx.x;
    const float* S; __hip_bfloat16* D; int N, K; int idx;
    if (b < 256)       { S = Wq; D = WqkvT;          K = 256; N = 256; idx = b * 256 + t; }
    else if (b < 512)  { S = Wk; D = WqkvT + 65536;  K = 256; N = 256; idx = (b - 256) * 256 + t; }
    else if (b < 768)  { S = Wv; D = WqkvT + 131072; K = 256; N = 256; idx = (b - 512) * 256 + t; }
    else if (b < 1024) { S = Wo; D = WoT;            K = 256; N = 256; idx = (b - 768) * 256 + t; }
    else if (b < 1536) { S = f1; D = f1T;            K = 256; N = 512; idx = (b - 1024) * 256 + t; }
    else               { S = f2; D = f2T;            K = 512; N = 256; idx = (b - 1536) * 256 + t; }
    int k = idx / N, n = idx % N;
    D[(size_t)n * K + k] = __float2bfloat16(S[idx]);
}

// ---------------------------------------------------------------------------
// CSR build
// ---------------------------------------------------------------------------
__global__ void hist_kernel(const int* __restrict__ dst, int* __restrict__ counts, int E)
{
    int e = blockIdx.x * blockDim.x + threadIdx.x;
    if (e < E) atomicAdd(&counts[dst[e]], 1);
}

__global__ void scan1_kernel(const int* __restrict__ counts, int* __restrict__ starts,
                             int* __restrict__ bsums, int N)
{
    __shared__ int tmp[256];
    int t = threadIdx.x;
    int i = blockIdx.x * 256 + t;
    int v = (i < N) ? counts[i] : 0;
    tmp[t] = v;
    __syncthreads();
    for (int off = 1; off < 256; off <<= 1) {
        int add = (t >= off) ? tmp[t - off] : 0;
        __syncthreads();
        tmp[t] += add;
        __syncthreads();
    }
    if (i < N) starts[i] = tmp[t] - v;
    if (t == 255) bsums[blockIdx.x] = tmp[255];
}

__global__ void scan2_kernel(const int* __restrict__ bsums, int* __restrict__ bexc, int NB)
{
    __shared__ int tmp[256];
    int t = threadIdx.x;
    int v = (t < NB) ? bsums[t] : 0;
    tmp[t] = v;
    __syncthreads();
    for (int off = 1; off < 256; off <<= 1) {
        int add = (t >= off) ? tmp[t - off] : 0;
        __syncthreads();
        tmp[t] += add;
        __syncthreads();
    }
    bexc[t] = tmp[t] - v;
}

__global__ void scan3_kernel(int* __restrict__ starts, const int* __restrict__ bexc,
                             const int* __restrict__ counts, int* __restrict__ cursor, int N)
{
    int t = threadIdx.x;
    int i = blockIdx.x * 256 + t;
    if (i < N) {
        int val = starts[i] + bexc[blockIdx.x];
        starts[i] = val;
        cursor[i] = val;
        if (i == N - 1) starts[N] = val + counts[i];
    }
}

__global__ void scatter_kernel(const int* __restrict__ src, const int* __restrict__ dst,
                               int* __restrict__ cursor, int* __restrict__ csr_src, int E)
{
    int e = blockIdx.x * blockDim.x + threadIdx.x;
    if (e < E) {
        int d = dst[e];
        int slot = atomicAdd(&cursor[d], 1);
        csr_src[slot] = src[e];
    }
}

// ---------------------------------------------------------------------------
// Attention over bf16 QKV packed [M][768]. One WAVE per node, 4 ch/thread.
// No max-subtraction (scores bounded ~|2|, exp safe; identical math to ref).
// Unrolled x2 with dual accumulators -> independent, pipelinable iterations.
// ---------------------------------------------------------------------------
__global__ __launch_bounds__(256) void attn_kernel(
    const __hip_bfloat16* __restrict__ QKV,
    const int* __restrict__ starts, const int* __restrict__ csr_src,
    __hip_bfloat16* __restrict__ out)   // [M][256]
{
    const int n = blockIdx.x * 4 + (threadIdx.x >> 6);
    const int lane = threadIdx.x & 63;
    const int c = lane << 2;                     // 4 channels per thread
    const size_t qb = (size_t)n * 768;
    ushort4 qv = *(const ushort4*)(QKV + qb + c);
    const float q0 = bf2f(qv.x), q1 = bf2f(qv.y), q2 = bf2f(qv.z), q3 = bf2f(qv.w);
    const int beg = starts[n], end = starts[n + 1];
    const float SC = 0.17677669529663688f;       // 32^-0.5

    float lA = 0.f, a0 = 0.f, a1 = 0.f, a2 = 0.f, a3 = 0.f;
    float lB = 0.f, b0 = 0.f, b1 = 0.f, b2 = 0.f, b3 = 0.f;
    int e = beg;
    for (; e + 2 <= end; e += 2) {
        int s0 = csr_src[e], s1 = csr_src[e + 1];
        const __hip_bfloat16* p0 = QKV + (size_t)s0 * 768 + 256 + c;
        const __hip_bfloat16* p1 = QKV + (size_t)s1 * 768 + 256 + c;
        ushort4 k0v = *(const ushort4*)p0;
        ushort4 k1v = *(const ushort4*)p1;
        ushort4 v0v = *(const ushort4*)(p0 + 256);
        ushort4 v1v = *(const ushort4*)(p1 + 256);
        float dA = q0 * bf2f(k0v.x) + q1 * bf2f(k0v.y) + q2 * bf2f(k0v.z) + q3 * bf2f(k0v.w);
        float dB = q0 * bf2f(k1v.x) + q1 * bf2f(k1v.y) + q2 * bf2f(k1v.z) + q3 * bf2f(k1v.w);
        dA += __shfl_xor(dA, 1, 8); dA += __shfl_xor(dA, 2, 8); dA += __shfl_xor(dA, 4, 8);
        dB += __shfl_xor(dB, 1, 8); dB += __shfl_xor(dB, 2, 8); dB += __shfl_xor(dB, 4, 8);
        float pA = __expf(dA * SC);
        float pB = __expf(dB * SC);
        lA += pA;
        a0 += pA * bf2f(v0v.x); a1 += pA * bf2f(v0v.y);
        a2 += pA * bf2f(v0v.z); a3 += pA * bf2f(v0v.w);
        lB += pB;
        b0 += pB * bf2f(v1v.x); b1 += pB * bf2f(v1v.y);
        b2 += pB * bf2f(v1v.z); b3 += pB * bf2f(v1v.w);
    }
    if (e < end) {
        int s0 = csr_src[e];
        const __hip_bfloat16* p0 = QKV + (size_t)s0 * 768 + 256 + c;
        ushort4 k0v = *(const ushort4*)p0;
        ushort4 v0v = *(const ushort4*)(p0 + 256);
        float dA = q0 * bf2f(k0v.x) + q1 * bf2f(k0v.y) + q2 * bf2f(k0v.z) + q3 * bf2f(k0v.w);
        dA += __shfl_xor(dA, 1, 8); dA += __shfl_xor(dA, 2, 8); dA += __shfl_xor(dA, 4, 8);
        float pA = __expf(dA * SC);
        lA += pA;
        a0 += pA * bf2f(v0v.x); a1 += pA * bf2f(v0v.y);
        a2 += pA * bf2f(v0v.z); a3 += pA * bf2f(v0v.w);
    }
    float l = lA + lB;
    a0 += b0; a1 += b1; a2 += b2; a3 += b3;
    float inv = 1.f / (l + 1e-8f);
    ushort4 o;
    o.x = f2bf_u16(a0 * inv);
    o.y = f2bf_u16(a1 * inv);
    o.z = f2bf_u16(a2 * inv);
    o.w = f2bf_u16(a3 * inv);
    *(ushort4*)(out + (size_t)n * DIM + c) = o;
}

// ---------------------------------------------------------------------------
// LayerNorm(a + b) * g + beta
// ---------------------------------------------------------------------------
template <typename TA, typename TB>
__global__ __launch_bounds__(256) void ln_kernel(
    const TA* __restrict__ a, const TB* __restrict__ b,
    const float* __restrict__ g, const float* __restrict__ beta,
    float* __restrict__ outf, __hip_bfloat16* __restrict__ outh)
{
    const int n = blockIdx.x;
    const int t = threadIdx.x;
    float x = to_f(a[(size_t)n * DIM + t]) + to_f(b[(size_t)n * DIM + t]);
    float s = x, s2 = x * x;
    #pragma unroll
    for (int off = 32; off >= 1; off >>= 1) {
        s  += __shfl_xor(s,  off, 64);
        s2 += __shfl_xor(s2, off, 64);
    }
    __shared__ float sb[4], sb2[4];
    int w = t >> 6;
    if ((t & 63) == 0) { sb[w] = s; sb2[w] = s2; }
    __syncthreads();
    float tot  = sb[0] + sb[1] + sb[2] + sb[3];
    float tot2 = sb2[0] + sb2[1] + sb2[2] + sb2[3];
    float mean = tot * (1.f / DIM);
    float var  = tot2 * (1.f / DIM) - mean * mean;
    float inv  = rsqrtf(var + 1e-5f);
    float o = (x - mean) * inv * g[t] + beta[t];
    if (outf) outf[(size_t)n * DIM + t] = o;
    if (outh) outh[(size_t)n * DIM + t] = __float2bfloat16(o);
}

// ---------------------------------------------------------------------------
extern "C" void kernel_launch(void* const* d_in, const int* in_sizes, int n_in,
                              void* d_out, int out_size, void* d_ws, size_t ws_size,
                              hipStream_t stream)
{
    const float* x     = (const float*)d_in[0];
    const int*   edge  = (const int*)d_in[1];
    const float* Wq    = (const float*)d_in[3];
    const float* Wk    = (const float*)d_in[4];
    const float* Wv    = (const float*)d_in[5];
    const float* Wo_w  = (const float*)d_in[6];
    const float* Wo_b  = (const float*)d_in[7];
    const float* ln1_g = (const float*)d_in[8];
    const float* ln1_b = (const float*)d_in[9];
    const float* ln2_g = (const float*)d_in[10];
    const float* ln2_b = (const float*)d_in[11];
    const float* fw1   = (const float*)d_in[12];
    const float* fb1   = (const float*)d_in[13];
    const float* fw2   = (const float*)d_in[14];
    const float* fb2   = (const float*)d_in[15];
    const int* srcA = edge;
    const int* dstA = edge + NEDGES;

    char* p = (char*)d_ws;
    const size_t QKV_SZ = (size_t)NNODES * 768 * 2;
    const size_t H_SZ   = (size_t)NNODES * DIM * 2;
    const size_t HID_SZ = (size_t)NNODES * HID_DIM * 2;
    __hip_bfloat16* QKVh = (__hip_bfloat16*)p;  p += QKV_SZ;
    __hip_bfloat16* AOh  = (__hip_bfloat16*)p;  p += H_SZ;
    __hip_bfloat16* O1h  = (__hip_bfloat16*)p;  p += H_SZ;
    __hip_bfloat16* HIDh = (__hip_bfloat16*)p;  p += HID_SZ;
    __hip_bfloat16* xh   = (__hip_bfloat16*)p;  p += H_SZ;
    __hip_bfloat16* WOh  = QKVh;                          // QKV dead after attn
    __hip_bfloat16* FFh  = QKVh + (size_t)NNODES * DIM;
    __hip_bfloat16* WqkvT = (__hip_bfloat16*)p; p += (size_t)768 * 256 * 2;
    __hip_bfloat16* WoT   = (__hip_bfloat16*)p; p += (size_t)256 * 256 * 2;
    __hip_bfloat16* fw1T  = (__hip_bfloat16*)p; p += (size_t)512 * 256 * 2;
    __hip_bfloat16* fw2T  = (__hip_bfloat16*)p; p += (size_t)256 * 512 * 2;
    int* counts = (int*)p;  p += sizeof(int) * NNODES;
    int* starts = (int*)p;  p += sizeof(int) * (NNODES + 1);
    int* bsums  = (int*)p;  p += sizeof(int) * 256;
    int* bexc   = (int*)p;  p += sizeof(int) * 256;
    int* cursor = (int*)p;  p += sizeof(int) * NNODES;
    int* csr    = (int*)p;  p += sizeof(int) * NEDGES;

    const int NB = (NNODES + 255) / 256;
    const int mT = (NNODES + 127) / 128;      // 391
    dim3 blk(256);

    // conversions
    conv_bf16_kernel<<<(NNODES * DIM / 4 + 255) / 256, blk, 0, stream>>>(x, xh, NNODES * DIM / 4);
    prep_w_kernel<<<2048, blk, 0, stream>>>(Wq, Wk, Wv, Wo_w, fw1, fw2, WqkvT, WoT, fw1T, fw2T);

    // CSR by dst
    hipMemsetAsync(counts, 0, sizeof(int) * NNODES, stream);
    hist_kernel<<<(NEDGES + 255) / 256, blk, 0, stream>>>(dstA, counts, NEDGES);
    scan1_kernel<<<NB, blk, 0, stream>>>(counts, starts, bsums, NNODES);
    scan2_kernel<<<1, blk, 0, stream>>>(bsums, bexc, NB);
    scan3_kernel<<<NB, blk, 0, stream>>>(starts, bexc, counts, cursor, NNODES);
    scatter_kernel<<<(NEDGES + 255) / 256, blk, 0, stream>>>(srcA, dstA, cursor, csr, NEDGES);

    // fused QKV projection
    gemm_bf16_kernel<<<mT * 6, blk, 0, stream>>>(xh, WqkvT, nullptr, QKVh, NNODES, 256, 768, 0);

    // segmented attention (1 wave per node, 4 nodes per block)
    attn_kernel<<<NNODES / 4, blk, 0, stream>>>(QKVh, starts, csr, AOh);

    // output projection + LN1
    gemm_bf16_kernel<<<mT * 2, blk, 0, stream>>>(AOh, WoT, Wo_b, WOh, NNODES, 256, 256, 0);
    ln_kernel<float, __hip_bfloat16><<<NNODES, blk, 0, stream>>>(x, WOh, ln1_g, ln1_b, nullptr, O1h);

    // FFN + LN2
    gemm_bf16_kernel<<<mT * 4, blk, 0, stream>>>(O1h, fw1T, fb1, HIDh, NNODES, 256, 512, 1);
    gemm_bf16_kernel<<<mT * 2, blk, 0, stream>>>(HIDh, fw2T, fb2, FFh, NNODES, 512, 256, 0);
    ln_kernel<__hip_bfloat16, __hip_bfloat16><<<NNODES, blk, 0, stream>>>(O1h, FFh, ln2_g, ln2_b, (float*)d_out, nullptr);
}

// Round 5
// 583.403 us; speedup vs baseline: 2.2358x; 1.0372x over previous
//
#include <hip/hip_runtime.h>
#include <hip/hip_bf16.h>
#include <math.h>

#define NNODES 50000
#define NEDGES 800000
#define DIM 256
#define HID_DIM 512

typedef short bf16x8 __attribute__((ext_vector_type(8)));
typedef float f32x4 __attribute__((ext_vector_type(4)));

__device__ __forceinline__ float to_f(float v) { return v; }
__device__ __forceinline__ float to_f(__hip_bfloat16 v) { return __bfloat162float(v); }
__device__ __forceinline__ float bf2f(unsigned short u) {
    return __uint_as_float(((unsigned)u) << 16);
}
__device__ __forceinline__ unsigned short f2bf_u16(float v) {
    __hip_bfloat16 h = __float2bfloat16(v);
    return __builtin_bit_cast(unsigned short, h);
}

// async global->LDS, 16B per lane; LDS dest = wave-uniform base + lane*16
#define GLD(g, l) __builtin_amdgcn_global_load_lds( \
    (const __attribute__((address_space(1))) unsigned int*)(g), \
    (__attribute__((address_space(3))) unsigned int*)(l), 16, 0, 0)

// ---------------------------------------------------------------------------
// bf16 MFMA GEMM: C[M,Nc](bf16) = A[M,K](bf16) @ BT[Nc,K]^T (+bias) (+GELU)
// 128x128 tile, BK=64, 4 waves. global_load_lds staging with GLOBAL-side XOR
// swizzle: LDS[r][ch] = G[r][ch ^ (r&7)] (16B chunks) -> fragment ds_read_b128
// lands <=2 lanes/bank (free); coalescing intact (permutation within 128B row).
// ---------------------------------------------------------------------------
__global__ __launch_bounds__(256) void gemm_bf16_kernel(
    const __hip_bfloat16* __restrict__ A,    // [M][K]
    const __hip_bfloat16* __restrict__ BT,   // [Nc][K]
    const float* __restrict__ bias,
    __hip_bfloat16* __restrict__ C,          // [M][Nc]
    int M, int K, int Nc, int act)
{
    __shared__ __align__(16) short As[128 * 64];   // 16 KB
    __shared__ __align__(16) short Bs[128 * 64];   // 16 KB

    const int nTilesN = Nc >> 7;
    const int bm = blockIdx.x / nTilesN;
    const int bn = blockIdx.x % nTilesN;
    const int m0 = bm << 7, n0 = bn << 7;
    const int t = threadIdx.x;
    const int wave = t >> 6, lane = t & 63;
    const int quad = lane >> 4, l16 = lane & 15;
    const int wm = (wave & 1) << 6, wn = (wave >> 1) << 6;

    f32x4 acc[4][4] = {};

    // staging geometry: chunk = 16B = 8 elems; 8 chunks/row; one GLD = 8 rows
    const int rr = lane >> 3;                  // row within 8-row block
    const int ch = lane & 7;                   // chunk within row
    const int gcol = ((ch ^ rr) << 3);         // swizzled global col (elems)
    size_t aoff[4], boff[4];
    #pragma unroll
    for (int g = 0; g < 4; ++g) {
        int r = (wave * 4 + g) * 8 + rr;       // 0..127
        int gm = m0 + r; if (gm >= M) gm = M - 1;
        aoff[g] = (size_t)gm * K + gcol;
        boff[g] = (size_t)(n0 + r) * K + gcol;
    }

    for (int k0 = 0; k0 < K; k0 += 64) {
        #pragma unroll
        for (int g = 0; g < 4; ++g)
            GLD(A + aoff[g] + k0, &As[(wave * 4 + g) * 512]);
        #pragma unroll
        for (int g = 0; g < 4; ++g)
            GLD(BT + boff[g] + k0, &Bs[(wave * 4 + g) * 512]);
        __syncthreads();
        #pragma unroll
        for (int kk = 0; kk < 2; ++kk) {
            bf16x8 af[4], bfv[4];
            const int cswz = quad + kk * 4;
            #pragma unroll
            for (int i = 0; i < 4; ++i) {
                int row = wm + i * 16 + l16;
                af[i] = *(const bf16x8*)(&As[row * 64 + ((cswz ^ (row & 7)) << 3)]);
            }
            #pragma unroll
            for (int j = 0; j < 4; ++j) {
                int row = wn + j * 16 + l16;
                bfv[j] = *(const bf16x8*)(&Bs[row * 64 + ((cswz ^ (row & 7)) << 3)]);
            }
            #pragma unroll
            for (int i = 0; i < 4; ++i)
                #pragma unroll
                for (int j = 0; j < 4; ++j)
                    acc[i][j] = __builtin_amdgcn_mfma_f32_16x16x32_bf16(af[i], bfv[j], acc[i][j], 0, 0, 0);
        }
        __syncthreads();
    }

    // C/D layout: col = lane&15, row = quad*4 + reg
    #pragma unroll
    for (int i = 0; i < 4; ++i) {
        int rbase = m0 + wm + i * 16 + quad * 4;
        #pragma unroll
        for (int r = 0; r < 4; ++r) {
            int rowg = rbase + r;
            if (rowg >= M) continue;
            #pragma unroll
            for (int j = 0; j < 4; ++j) {
                int col = n0 + wn + j * 16 + l16;
                float v = acc[i][j][r];
                if (bias) v += bias[col];
                if (act) v = 0.5f * v * (1.f + erff(v * 0.70710678118654752f));
                C[(size_t)rowg * Nc + col] = __float2bfloat16(v);
            }
        }
    }
}

// ---------------------------------------------------------------------------
// fp32 -> bf16 (4 elems/thread)
// ---------------------------------------------------------------------------
__global__ void conv_bf16_kernel(const float* __restrict__ in,
                                 __hip_bfloat16* __restrict__ out, int n4)
{
    int i = blockIdx.x * 256 + threadIdx.x;
    if (i < n4) {
        float4 v = ((const float4*)in)[i];
        __hip_bfloat162 p0, p1;
        p0.x = __float2bfloat16(v.x); p0.y = __float2bfloat16(v.y);
        p1.x = __float2bfloat16(v.z); p1.y = __float2bfloat16(v.w);
        ((__hip_bfloat162*)out)[i * 2]     = p0;
        ((__hip_bfloat162*)out)[i * 2 + 1] = p1;
    }
}

// all weight transposes fused: W[K][N] fp32 -> WT[N][K] bf16 (grid = 2048 blocks)
__global__ void prep_w_kernel(const float* __restrict__ Wq, const float* __restrict__ Wk,
                              const float* __restrict__ Wv, const float* __restrict__ Wo,
                              const float* __restrict__ f1, const float* __restrict__ f2,
                              __hip_bfloat16* __restrict__ WqkvT, __hip_bfloat16* __restrict__ WoT,
                              __hip_bfloat16* __restrict__ f1T, __hip_bfloat16* __restrict__ f2T)
{
    int b = blockIdx.x, t = threadIdx.x;
    const float* S; __hip_bfloat16* D; int N, K; int idx;
    if (b < 256)       { S = Wq; D = WqkvT;          K = 256; N = 256; idx = b * 256 + t; }
    else if (b < 512)  { S = Wk; D = WqkvT + 65536;  K = 256; N = 256; idx = (b - 256) * 256 + t; }
    else if (b < 768)  { S = Wv; D = WqkvT + 131072; K = 256; N = 256; idx = (b - 512) * 256 + t; }
    else if (b < 1024) { S = Wo; D = WoT;            K = 256; N = 256; idx = (b - 768) * 256 + t; }
    else if (b < 1536) { S = f1; D = f1T;            K = 256; N = 512; idx = (b - 1024) * 256 + t; }
    else               { S = f2; D = f2T;            K = 512; N = 256; idx = (b - 1536) * 256 + t; }
    int k = idx / N, n = idx % N;
    D[(size_t)n * K + k] = __float2bfloat16(S[idx]);
}

// ---------------------------------------------------------------------------
// CSR build
// ---------------------------------------------------------------------------
__global__ void hist_kernel(const int* __restrict__ dst, int* __restrict__ counts, int E)
{
    int e = blockIdx.x * blockDim.x + threadIdx.x;
    if (e < E) atomicAdd(&counts[dst[e]], 1);
}

__global__ void scan1_kernel(const int* __restrict__ counts, int* __restrict__ starts,
                             int* __restrict__ bsums, int N)
{
    __shared__ int tmp[256];
    int t = threadIdx.x;
    int i = blockIdx.x * 256 + t;
    int v = (i < N) ? counts[i] : 0;
    tmp[t] = v;
    __syncthreads();
    for (int off = 1; off < 256; off <<= 1) {
        int add = (t >= off) ? tmp[t - off] : 0;
        __syncthreads();
        tmp[t] += add;
        __syncthreads();
    }
    if (i < N) starts[i] = tmp[t] - v;
    if (t == 255) bsums[blockIdx.x] = tmp[255];
}

__global__ void scan2_kernel(const int* __restrict__ bsums, int* __restrict__ bexc, int NB)
{
    __shared__ int tmp[256];
    int t = threadIdx.x;
    int v = (t < NB) ? bsums[t] : 0;
    tmp[t] = v;
    __syncthreads();
    for (int off = 1; off < 256; off <<= 1) {
        int add = (t >= off) ? tmp[t - off] : 0;
        __syncthreads();
        tmp[t] += add;
        __syncthreads();
    }
    bexc[t] = tmp[t] - v;
}

__global__ void scan3_kernel(int* __restrict__ starts, const int* __restrict__ bexc,
                             const int* __restrict__ counts, int* __restrict__ cursor, int N)
{
    int t = threadIdx.x;
    int i = blockIdx.x * 256 + t;
    if (i < N) {
        int val = starts[i] + bexc[blockIdx.x];
        starts[i] = val;
        cursor[i] = val;
        if (i == N - 1) starts[N] = val + counts[i];
    }
}

__global__ void scatter_kernel(const int* __restrict__ src, const int* __restrict__ dst,
                               int* __restrict__ cursor, int* __restrict__ csr_src, int E)
{
    int e = blockIdx.x * blockDim.x + threadIdx.x;
    if (e < E) {
        int d = dst[e];
        int slot = atomicAdd(&cursor[d], 1);
        csr_src[slot] = src[e];
    }
}

// ---------------------------------------------------------------------------
// Attention over bf16 QKV packed [M][768]. One WAVE per node, 4 ch/thread.
// No max-subtraction (scores bounded ~|2|; exp-shift cancels exactly).
// Unrolled x4 with 4 independent accumulator sets -> 8 loads in flight.
// ---------------------------------------------------------------------------
__global__ __launch_bounds__(256) void attn_kernel(
    const __hip_bfloat16* __restrict__ QKV,
    const int* __restrict__ starts, const int* __restrict__ csr_src,
    __hip_bfloat16* __restrict__ out)   // [M][256]
{
    const int n = blockIdx.x * 4 + (threadIdx.x >> 6);
    const int lane = threadIdx.x & 63;
    const int c = lane << 2;                     // 4 channels per thread
    const size_t qb = (size_t)n * 768;
    ushort4 qv = *(const ushort4*)(QKV + qb + c);
    const float q0 = bf2f(qv.x), q1 = bf2f(qv.y), q2 = bf2f(qv.z), q3 = bf2f(qv.w);
    const int beg = starts[n], end = starts[n + 1];
    const float SC = 0.17677669529663688f;       // 32^-0.5

    float lA = 0.f, lB = 0.f, lC = 0.f, lD = 0.f;
    f32x4 aA = {0,0,0,0}, aB = {0,0,0,0}, aC = {0,0,0,0}, aD = {0,0,0,0};
    int e = beg;
    for (; e + 4 <= end; e += 4) {
        int s0 = csr_src[e], s1 = csr_src[e + 1], s2 = csr_src[e + 2], s3 = csr_src[e + 3];
        const __hip_bfloat16* p0 = QKV + (size_t)s0 * 768 + 256 + c;
        const __hip_bfloat16* p1 = QKV + (size_t)s1 * 768 + 256 + c;
        const __hip_bfloat16* p2 = QKV + (size_t)s2 * 768 + 256 + c;
        const __hip_bfloat16* p3 = QKV + (size_t)s3 * 768 + 256 + c;
        ushort4 k0v = *(const ushort4*)p0;
        ushort4 k1v = *(const ushort4*)p1;
        ushort4 k2v = *(const ushort4*)p2;
        ushort4 k3v = *(const ushort4*)p3;
        ushort4 v0v = *(const ushort4*)(p0 + 256);
        ushort4 v1v = *(const ushort4*)(p1 + 256);
        ushort4 v2v = *(const ushort4*)(p2 + 256);
        ushort4 v3v = *(const ushort4*)(p3 + 256);
        float dA = q0 * bf2f(k0v.x) + q1 * bf2f(k0v.y) + q2 * bf2f(k0v.z) + q3 * bf2f(k0v.w);
        float dB = q0 * bf2f(k1v.x) + q1 * bf2f(k1v.y) + q2 * bf2f(k1v.z) + q3 * bf2f(k1v.w);
        float dC = q0 * bf2f(k2v.x) + q1 * bf2f(k2v.y) + q2 * bf2f(k2v.z) + q3 * bf2f(k2v.w);
        float dD = q0 * bf2f(k3v.x) + q1 * bf2f(k3v.y) + q2 * bf2f(k3v.z) + q3 * bf2f(k3v.w);
        dA += __shfl_xor(dA, 1, 8); dA += __shfl_xor(dA, 2, 8); dA += __shfl_xor(dA, 4, 8);
        dB += __shfl_xor(dB, 1, 8); dB += __shfl_xor(dB, 2, 8); dB += __shfl_xor(dB, 4, 8);
        dC += __shfl_xor(dC, 1, 8); dC += __shfl_xor(dC, 2, 8); dC += __shfl_xor(dC, 4, 8);
        dD += __shfl_xor(dD, 1, 8); dD += __shfl_xor(dD, 2, 8); dD += __shfl_xor(dD, 4, 8);
        float pA = __expf(dA * SC), pB = __expf(dB * SC);
        float pC = __expf(dC * SC), pD = __expf(dD * SC);
        lA += pA; lB += pB; lC += pC; lD += pD;
        aA[0] += pA * bf2f(v0v.x); aA[1] += pA * bf2f(v0v.y); aA[2] += pA * bf2f(v0v.z); aA[3] += pA * bf2f(v0v.w);
        aB[0] += pB * bf2f(v1v.x); aB[1] += pB * bf2f(v1v.y); aB[2] += pB * bf2f(v1v.z); aB[3] += pB * bf2f(v1v.w);
        aC[0] += pC * bf2f(v2v.x); aC[1] += pC * bf2f(v2v.y); aC[2] += pC * bf2f(v2v.z); aC[3] += pC * bf2f(v2v.w);
        aD[0] += pD * bf2f(v3v.x); aD[1] += pD * bf2f(v3v.y); aD[2] += pD * bf2f(v3v.z); aD[3] += pD * bf2f(v3v.w);
    }
    for (; e < end; ++e) {
        int s0 = csr_src[e];
        const __hip_bfloat16* p0 = QKV + (size_t)s0 * 768 + 256 + c;
        ushort4 k0v = *(const ushort4*)p0;
        ushort4 v0v = *(const ushort4*)(p0 + 256);
        float dA = q0 * bf2f(k0v.x) + q1 * bf2f(k0v.y) + q2 * bf2f(k0v.z) + q3 * bf2f(k0v.w);
        dA += __shfl_xor(dA, 1, 8); dA += __shfl_xor(dA, 2, 8); dA += __shfl_xor(dA, 4, 8);
        float pA = __expf(dA * SC);
        lA += pA;
        aA[0] += pA * bf2f(v0v.x); aA[1] += pA * bf2f(v0v.y);
        aA[2] += pA * bf2f(v0v.z); aA[3] += pA * bf2f(v0v.w);
    }
    float l = (lA + lB) + (lC + lD);
    float o0 = (aA[0] + aB[0]) + (aC[0] + aD[0]);
    float o1 = (aA[1] + aB[1]) + (aC[1] + aD[1]);
    float o2 = (aA[2] + aB[2]) + (aC[2] + aD[2]);
    float o3 = (aA[3] + aB[3]) + (aC[3] + aD[3]);
    float inv = 1.f / (l + 1e-8f);
    ushort4 o;
    o.x = f2bf_u16(o0 * inv);
    o.y = f2bf_u16(o1 * inv);
    o.z = f2bf_u16(o2 * inv);
    o.w = f2bf_u16(o3 * inv);
    *(ushort4*)(out + (size_t)n * DIM + c) = o;
}

// ---------------------------------------------------------------------------
// LayerNorm(a + b) * g + beta. One WAVE per row, 4 ch/thread, shfl-only reduce.
// ---------------------------------------------------------------------------
template <typename TA>
__global__ __launch_bounds__(256) void ln_kernel(
    const TA* __restrict__ a, const __hip_bfloat16* __restrict__ b,
    const float* __restrict__ g, const float* __restrict__ beta,
    float* __restrict__ outf, __hip_bfloat16* __restrict__ outh)
{
    const int n = blockIdx.x * 4 + (threadIdx.x >> 6);
    const int lane = threadIdx.x & 63;
    const int c = lane << 2;
    float xv[4];
    ushort4 bv = *(const ushort4*)(b + (size_t)n * DIM + c);
    xv[0] = bf2f(bv.x); xv[1] = bf2f(bv.y); xv[2] = bf2f(bv.z); xv[3] = bf2f(bv.w);
    if constexpr (sizeof(TA) == 4) {
        float4 av = *(const float4*)(a + (size_t)n * DIM + c);
        xv[0] += av.x; xv[1] += av.y; xv[2] += av.z; xv[3] += av.w;
    } else {
        ushort4 av = *(const ushort4*)((const unsigned short*)a + (size_t)n * DIM + c);
        xv[0] += bf2f(av.x); xv[1] += bf2f(av.y); xv[2] += bf2f(av.z); xv[3] += bf2f(av.w);
    }
    float s  = (xv[0] + xv[1]) + (xv[2] + xv[3]);
    float s2 = (xv[0]*xv[0] + xv[1]*xv[1]) + (xv[2]*xv[2] + xv[3]*xv[3]);
    #pragma unroll
    for (int off = 1; off < 64; off <<= 1) {
        s  += __shfl_xor(s,  off, 64);
        s2 += __shfl_xor(s2, off, 64);
    }
    float mean = s * (1.f / DIM);
    float var  = s2 * (1.f / DIM) - mean * mean;
    float inv  = rsqrtf(var + 1e-5f);
    float4 gv = *(const float4*)(g + c);
    float4 bt = *(const float4*)(beta + c);
    float o0 = (xv[0] - mean) * inv * gv.x + bt.x;
    float o1 = (xv[1] - mean) * inv * gv.y + bt.y;
    float o2 = (xv[2] - mean) * inv * gv.z + bt.z;
    float o3 = (xv[3] - mean) * inv * gv.w + bt.w;
    if (outf) {
        *(float4*)(outf + (size_t)n * DIM + c) = make_float4(o0, o1, o2, o3);
    } else {
        ushort4 o;
        o.x = f2bf_u16(o0); o.y = f2bf_u16(o1); o.z = f2bf_u16(o2); o.w = f2bf_u16(o3);
        *(ushort4*)(outh + (size_t)n * DIM + c) = o;
    }
}

// ---------------------------------------------------------------------------
extern "C" void kernel_launch(void* const* d_in, const int* in_sizes, int n_in,
                              void* d_out, int out_size, void* d_ws, size_t ws_size,
                              hipStream_t stream)
{
    const float* x     = (const float*)d_in[0];
    const int*   edge  = (const int*)d_in[1];
    const float* Wq    = (const float*)d_in[3];
    const float* Wk    = (const float*)d_in[4];
    const float* Wv    = (const float*)d_in[5];
    const float* Wo_w  = (const float*)d_in[6];
    const float* Wo_b  = (const float*)d_in[7];
    const float* ln1_g = (const float*)d_in[8];
    const float* ln1_b = (const float*)d_in[9];
    const float* ln2_g = (const float*)d_in[10];
    const float* ln2_b = (const float*)d_in[11];
    const float* fw1   = (const float*)d_in[12];
    const float* fb1   = (const float*)d_in[13];
    const float* fw2   = (const float*)d_in[14];
    const float* fb2   = (const float*)d_in[15];
    const int* srcA = edge;
    const int* dstA = edge + NEDGES;

    char* p = (char*)d_ws;
    const size_t QKV_SZ = (size_t)NNODES * 768 * 2;
    const size_t H_SZ   = (size_t)NNODES * DIM * 2;
    const size_t HID_SZ = (size_t)NNODES * HID_DIM * 2;
    __hip_bfloat16* QKVh = (__hip_bfloat16*)p;  p += QKV_SZ;
    __hip_bfloat16* AOh  = (__hip_bfloat16*)p;  p += H_SZ;
    __hip_bfloat16* O1h  = (__hip_bfloat16*)p;  p += H_SZ;
    __hip_bfloat16* HIDh = (__hip_bfloat16*)p;  p += HID_SZ;
    __hip_bfloat16* xh   = (__hip_bfloat16*)p;  p += H_SZ;
    __hip_bfloat16* WOh  = QKVh;                          // QKV dead after attn
    __hip_bfloat16* FFh  = QKVh + (size_t)NNODES * DIM;
    __hip_bfloat16* WqkvT = (__hip_bfloat16*)p; p += (size_t)768 * 256 * 2;
    __hip_bfloat16* WoT   = (__hip_bfloat16*)p; p += (size_t)256 * 256 * 2;
    __hip_bfloat16* fw1T  = (__hip_bfloat16*)p; p += (size_t)512 * 256 * 2;
    __hip_bfloat16* fw2T  = (__hip_bfloat16*)p; p += (size_t)256 * 512 * 2;
    int* counts = (int*)p;  p += sizeof(int) * NNODES;
    int* starts = (int*)p;  p += sizeof(int) * (NNODES + 1);
    int* bsums  = (int*)p;  p += sizeof(int) * 256;
    int* bexc   = (int*)p;  p += sizeof(int) * 256;
    int* cursor = (int*)p;  p += sizeof(int) * NNODES;
    int* csr    = (int*)p;  p += sizeof(int) * NEDGES;

    const int NB = (NNODES + 255) / 256;
    const int mT = (NNODES + 127) / 128;      // 391
    dim3 blk(256);

    // conversions
    conv_bf16_kernel<<<(NNODES * DIM / 4 + 255) / 256, blk, 0, stream>>>(x, xh, NNODES * DIM / 4);
    prep_w_kernel<<<2048, blk, 0, stream>>>(Wq, Wk, Wv, Wo_w, fw1, fw2, WqkvT, WoT, fw1T, fw2T);

    // CSR by dst
    hipMemsetAsync(counts, 0, sizeof(int) * NNODES, stream);
    hist_kernel<<<(NEDGES + 255) / 256, blk, 0, stream>>>(dstA, counts, NEDGES);
    scan1_kernel<<<NB, blk, 0, stream>>>(counts, starts, bsums, NNODES);
    scan2_kernel<<<1, blk, 0, stream>>>(bsums, bexc, NB);
    scan3_kernel<<<NB, blk, 0, stream>>>(starts, bexc, counts, cursor, NNODES);
    scatter_kernel<<<(NEDGES + 255) / 256, blk, 0, stream>>>(srcA, dstA, cursor, csr, NEDGES);

    // fused QKV projection
    gemm_bf16_kernel<<<mT * 6, blk, 0, stream>>>(xh, WqkvT, nullptr, QKVh, NNODES, 256, 768, 0);

    // segmented attention (1 wave per node, 4 nodes per block)
    attn_kernel<<<NNODES / 4, blk, 0, stream>>>(QKVh, starts, csr, AOh);

    // output projection + LN1
    gemm_bf16_kernel<<<mT * 2, blk, 0, stream>>>(AOh, WoT, Wo_b, WOh, NNODES, 256, 256, 0);
    ln_kernel<float><<<(NNODES + 3) / 4, blk, 0, stream>>>(x, WOh, ln1_g, ln1_b, nullptr, O1h);

    // FFN + LN2
    gemm_bf16_kernel<<<mT * 4, blk, 0, stream>>>(O1h, fw1T, fb1, HIDh, NNODES, 256, 512, 1);
    gemm_bf16_kernel<<<mT * 2, blk, 0, stream>>>(HIDh, fw2T, fb2, FFh, NNODES, 512, 256, 0);
    ln_kernel<__hip_bfloat16><<<(NNODES + 3) / 4, blk, 0, stream>>>(O1h, FFh, ln2_g, ln2_b, (float*)d_out, nullptr);
}

// Round 7
// 520.101 us; speedup vs baseline: 2.5080x; 1.1217x over previous
//
#include <hip/hip_runtime.h>
#include <hip/hip_bf16.h>
#include <math.h>

#define NNODES 50000
#define NEDGES 800000
#define DIM 256
#define HID_DIM 512

typedef short bf16x8 __attribute__((ext_vector_type(8)));
typedef float f32x4 __attribute__((ext_vector_type(4)));

__device__ __forceinline__ float bf2f(unsigned short u) {
    return __uint_as_float(((unsigned)u) << 16);
}
__device__ __forceinline__ unsigned short f2bf_u16(float v) {
    __hip_bfloat16 h = __float2bfloat16(v);
    return __builtin_bit_cast(unsigned short, h);
}
__device__ __forceinline__ void unpack8(uint4 v, float* f) {
    f[0] = __uint_as_float(v.x << 16); f[1] = __uint_as_float(v.x & 0xffff0000u);
    f[2] = __uint_as_float(v.y << 16); f[3] = __uint_as_float(v.y & 0xffff0000u);
    f[4] = __uint_as_float(v.z << 16); f[5] = __uint_as_float(v.z & 0xffff0000u);
    f[6] = __uint_as_float(v.w << 16); f[7] = __uint_as_float(v.w & 0xffff0000u);
}
__device__ __forceinline__ unsigned pk2(float a, float b) {
    return (unsigned)f2bf_u16(a) | ((unsigned)f2bf_u16(b) << 16);
}
__device__ __forceinline__ uint4 pack8(const float* f) {
    return make_uint4(pk2(f[0],f[1]), pk2(f[2],f[3]), pk2(f[4],f[5]), pk2(f[6],f[7]));
}

// async global->LDS, 16B per lane; LDS dest = wave-uniform base + lane*16
#define GLD(g, l) __builtin_amdgcn_global_load_lds( \
    (const __attribute__((address_space(1))) unsigned int*)(g), \
    (__attribute__((address_space(3))) unsigned int*)(l), 16, 0, 0)

// ---------------------------------------------------------------------------
// bf16 MFMA GEMM, 64x256 tile, BK=64, 4 waves (each 64x64).
// MODE 0: C=bf16(A@B^T + bias)
// MODE 1: C=bf16(gelu(A@B^T + bias))
// MODE 2: C=bf16(LN(resid_f32 + A@B^T + bias))   (Nc == 256)
// MODE 3: C=f32 (LN(resid_bf16 + A@B^T + bias))  (Nc == 256)
// LN path stays fp32 in registers: bias+resid added to acc, stats via shfl +
// 2KB LDS cross-wave exchange, normalize from acc. Only the final store is
// rounded (bf16 out) — strictly more precise than a separate LN kernel on a
// bf16 intermediate.
// ---------------------------------------------------------------------------
template <int MODE>
__global__ __launch_bounds__(256) void gemm_bf16_kernel(
    const __hip_bfloat16* __restrict__ A,    // [M][K]
    const __hip_bfloat16* __restrict__ BT,   // [Nc][K]
    const float* __restrict__ bias,          // [Nc] or null
    const void* __restrict__ resid,          // [M][256] f32 (MODE2) / bf16 (MODE3)
    const float* __restrict__ gam, const float* __restrict__ bet,
    __hip_bfloat16* __restrict__ Ch,         // bf16 out (MODE 0/1/2)
    float* __restrict__ Cf,                  // f32 out (MODE 3)
    int M, int K, int Nc)
{
    __shared__ __align__(16) char ldsbuf[40960];
    short* As = (short*)ldsbuf;               // [64][64]   8 KB
    short* Bs = (short*)(ldsbuf + 8192);      // [256][64] 32 KB
    short* Cs = (short*)ldsbuf;               // [64][264] bf16, 33792 B (epilogue)
    float* red = (float*)(ldsbuf + 33792);    // [2][64][4] stats, 2 KB (epilogue)

    const int nTilesN = Nc >> 8;
    const int bm = blockIdx.x / nTilesN;
    const int bn = blockIdx.x - bm * nTilesN;
    const int m0 = bm << 6, n0 = bn << 8;
    const int t = threadIdx.x;
    const int wave = t >> 6, lane = t & 63;
    const int quad = lane >> 4, l16 = lane & 15;
    const int wn = wave << 6;

    f32x4 acc[4][4] = {};

    const int rr = lane >> 3, chk = lane & 7;
    const int gcol = (chk ^ rr) << 3;
    size_t aoff[2], boff[8];
    #pragma unroll
    for (int g = 0; g < 2; ++g) {
        int gm = m0 + (wave * 2 + g) * 8 + rr;
        if (gm >= M) gm = M - 1;
        aoff[g] = (size_t)gm * K + gcol;
    }
    #pragma unroll
    for (int g = 0; g < 8; ++g)
        boff[g] = (size_t)(n0 + (wave * 8 + g) * 8 + rr) * K + gcol;

    for (int k0 = 0; k0 < K; k0 += 64) {
        #pragma unroll
        for (int g = 0; g < 2; ++g)
            GLD(A + aoff[g] + k0, &As[(wave * 2 + g) * 512]);
        #pragma unroll
        for (int g = 0; g < 8; ++g)
            GLD(BT + boff[g] + k0, &Bs[(wave * 8 + g) * 512]);
        __syncthreads();
        #pragma unroll
        for (int kk = 0; kk < 2; ++kk) {
            const int cswz = quad + kk * 4;
            bf16x8 af[4], bfv[4];
            #pragma unroll
            for (int i = 0; i < 4; ++i) {
                int row = i * 16 + l16;
                af[i] = *(const bf16x8*)(&As[row * 64 + ((cswz ^ (row & 7)) << 3)]);
            }
            #pragma unroll
            for (int j = 0; j < 4; ++j) {
                int row = wn + j * 16 + l16;
                bfv[j] = *(const bf16x8*)(&Bs[row * 64 + ((cswz ^ (row & 7)) << 3)]);
            }
            #pragma unroll
            for (int i = 0; i < 4; ++i)
                #pragma unroll
                for (int j = 0; j < 4; ++j)
                    acc[i][j] = __builtin_amdgcn_mfma_f32_16x16x32_bf16(af[i], bfv[j], acc[i][j], 0, 0, 0);
        }
        __syncthreads();
    }

    // C/D layout: col = wn + j*16 + l16, row = i*16 + quad*4 + r
    float bv[4];
    #pragma unroll
    for (int j = 0; j < 4; ++j)
        bv[j] = bias ? bias[n0 + wn + j * 16 + l16] : 0.f;

    if constexpr (MODE <= 1) {
        #pragma unroll
        for (int i = 0; i < 4; ++i)
            #pragma unroll
            for (int j = 0; j < 4; ++j) {
                int col = wn + j * 16 + l16;
                #pragma unroll
                for (int r = 0; r < 4; ++r) {
                    int row = i * 16 + quad * 4 + r;
                    float v = acc[i][j][r] + bv[j];
                    if (MODE == 1) v = 0.5f * v * (1.f + erff(v * 0.70710678118654752f));
                    Cs[row * 264 + col] = (short)f2bf_u16(v);
                }
            }
        __syncthreads();
        #pragma unroll
        for (int it = 0; it < 8; ++it) {
            int ci = it * 256 + t;
            int row = ci >> 5, ck = ci & 31;
            int gm = m0 + row;
            if (gm < M) {
                uint4 v = *(const uint4*)(&Cs[row * 264 + ck * 8]);
                *(uint4*)(&Ch[(size_t)gm * Nc + n0 + ck * 8]) = v;
            }
        }
    } else {
        // ---- fp32 LN epilogue ----
        // bias + residual into fp32 acc (per-lane gather; 64B-contiguous per quad)
        #pragma unroll
        for (int i = 0; i < 4; ++i)
            #pragma unroll
            for (int r = 0; r < 4; ++r) {
                int rowg = m0 + i * 16 + quad * 4 + r;
                int rc = rowg < M ? rowg : M - 1;
                #pragma unroll
                for (int j = 0; j < 4; ++j) {
                    int col = wn + j * 16 + l16;
                    float rv;
                    if constexpr (MODE == 2)
                        rv = ((const float*)resid)[(size_t)rc * 256 + col];
                    else
                        rv = bf2f(((const unsigned short*)resid)[(size_t)rc * 256 + col]);
                    acc[i][j][r] += bv[j] + rv;
                }
            }
        // per-row sums: 4 cols/lane -> reduce over 16 l16-lanes -> LDS cross-wave
        #pragma unroll
        for (int i = 0; i < 4; ++i)
            #pragma unroll
            for (int r = 0; r < 4; ++r) {
                float ss = (acc[i][0][r] + acc[i][1][r]) + (acc[i][2][r] + acc[i][3][r]);
                float qq = (acc[i][0][r]*acc[i][0][r] + acc[i][1][r]*acc[i][1][r])
                         + (acc[i][2][r]*acc[i][2][r] + acc[i][3][r]*acc[i][3][r]);
                ss += __shfl_xor(ss, 1); ss += __shfl_xor(ss, 2);
                ss += __shfl_xor(ss, 4); ss += __shfl_xor(ss, 8);
                qq += __shfl_xor(qq, 1); qq += __shfl_xor(qq, 2);
                qq += __shfl_xor(qq, 4); qq += __shfl_xor(qq, 8);
                if (l16 == 0) {
                    int row = i * 16 + quad * 4 + r;
                    red[row * 4 + wave]       = ss;
                    red[256 + row * 4 + wave] = qq;
                }
            }
        __syncthreads();
        float mean_[4][4], inv_[4][4];
        #pragma unroll
        for (int i = 0; i < 4; ++i)
            #pragma unroll
            for (int r = 0; r < 4; ++r) {
                int row = i * 16 + quad * 4 + r;
                float4 sv = *(const float4*)&red[row * 4];
                float4 qv = *(const float4*)&red[256 + row * 4];
                float s  = (sv.x + sv.y) + (sv.z + sv.w);
                float q  = (qv.x + qv.y) + (qv.z + qv.w);
                float mean = s * (1.f / 256.f);
                float var  = q * (1.f / 256.f) - mean * mean;
                mean_[i][r] = mean;
                inv_[i][r]  = rsqrtf(var + 1e-5f);
            }
        float gv[4], btv[4];
        #pragma unroll
        for (int j = 0; j < 4; ++j) {
            int col = wn + j * 16 + l16;
            gv[j] = gam[col]; btv[j] = bet[col];
        }
        if constexpr (MODE == 2) {
            #pragma unroll
            for (int i = 0; i < 4; ++i)
                #pragma unroll
                for (int j = 0; j < 4; ++j) {
                    int col = wn + j * 16 + l16;
                    #pragma unroll
                    for (int r = 0; r < 4; ++r) {
                        int row = i * 16 + quad * 4 + r;
                        float v = (acc[i][j][r] - mean_[i][r]) * inv_[i][r] * gv[j] + btv[j];
                        Cs[row * 264 + col] = (short)f2bf_u16(v);
                    }
                }
            __syncthreads();
            #pragma unroll
            for (int it = 0; it < 8; ++it) {
                int ci = it * 256 + t;
                int row = ci >> 5, ck = ci & 31;
                int gm = m0 + row;
                if (gm < M) {
                    uint4 v = *(const uint4*)(&Cs[row * 264 + ck * 8]);
                    *(uint4*)(&Ch[(size_t)gm * 256 + ck * 8]) = v;
                }
            }
        } else {
            #pragma unroll
            for (int i = 0; i < 4; ++i)
                #pragma unroll
                for (int r = 0; r < 4; ++r) {
                    int rowg = m0 + i * 16 + quad * 4 + r;
                    if (rowg < M) {
                        #pragma unroll
                        for (int j = 0; j < 4; ++j) {
                            int col = wn + j * 16 + l16;
                            float v = (acc[i][j][r] - mean_[i][r]) * inv_[i][r] * gv[j] + btv[j];
                            Cf[(size_t)rowg * 256 + col] = v;
                        }
                    }
                }
        }
    }
}

// ---------------------------------------------------------------------------
// fp32 -> bf16 (4 elems/thread)
// ---------------------------------------------------------------------------
__global__ void conv_bf16_kernel(const float* __restrict__ in,
                                 __hip_bfloat16* __restrict__ out, int n4)
{
    int i = blockIdx.x * 256 + threadIdx.x;
    if (i < n4) {
        float4 v = ((const float4*)in)[i];
        float f[4] = {v.x, v.y, v.z, v.w};
        uint2 o = make_uint2(pk2(f[0], f[1]), pk2(f[2], f[3]));
        ((uint2*)out)[i] = o;
    }
}

// ---------------------------------------------------------------------------
// Weight prep: W[K][N] fp32 -> WT[N][K] bf16, LDS-tiled 64x64
// ---------------------------------------------------------------------------
__global__ __launch_bounds__(256) void prep_w_kernel(
    const float* __restrict__ Wq, const float* __restrict__ Wk,
    const float* __restrict__ Wv, const float* __restrict__ Wo,
    const float* __restrict__ f1, const float* __restrict__ f2,
    unsigned short* __restrict__ WqkvT, unsigned short* __restrict__ WoT,
    unsigned short* __restrict__ f1T, unsigned short* __restrict__ f2T)
{
    __shared__ unsigned short Ts[64 * 72];
    int b = blockIdx.x, t = threadIdx.x;
    const float* S; unsigned short* D; int K, N, tile;
    if (b < 64) {
        int m = b >> 4; tile = b & 15; K = 256; N = 256;
        S = (m == 0) ? Wq : (m == 1) ? Wk : (m == 2) ? Wv : Wo;
        D = (m == 3) ? WoT : WqkvT + m * 65536;
    } else if (b < 96) { tile = b - 64; S = f1; D = f1T; K = 256; N = 512; }
    else               { tile = b - 96; S = f2; D = f2T; K = 512; N = 256; }
    int tilesN = N >> 6;
    int k0 = (tile / tilesN) << 6, n0 = (tile % tilesN) << 6;
    #pragma unroll
    for (int it = 0; it < 16; ++it) {
        int idx = it * 256 + t;
        int r = idx >> 6, c = idx & 63;
        Ts[r * 72 + c] = f2bf_u16(S[(size_t)(k0 + r) * N + n0 + c]);
    }
    __syncthreads();
    #pragma unroll
    for (int it = 0; it < 16; ++it) {
        int idx = it * 256 + t;
        int r = idx >> 6, c = idx & 63;
        D[(size_t)(n0 + r) * K + k0 + c] = Ts[c * 72 + r];
    }
}

// ---------------------------------------------------------------------------
// CSR build
// ---------------------------------------------------------------------------
__global__ void hist_kernel(const int* __restrict__ dst, int* __restrict__ counts, int E)
{
    int e = blockIdx.x * blockDim.x + threadIdx.x;
    if (e < E) atomicAdd(&counts[dst[e]], 1);
}

__global__ void scan1_kernel(const int* __restrict__ counts, int* __restrict__ starts,
                             int* __restrict__ bsums, int N)
{
    __shared__ int tmp[256];
    int t = threadIdx.x;
    int i = blockIdx.x * 256 + t;
    int v = (i < N) ? counts[i] : 0;
    tmp[t] = v;
    __syncthreads();
    for (int off = 1; off < 256; off <<= 1) {
        int add = (t >= off) ? tmp[t - off] : 0;
        __syncthreads();
        tmp[t] += add;
        __syncthreads();
    }
    if (i < N) starts[i] = tmp[t] - v;
    if (t == 255) bsums[blockIdx.x] = tmp[255];
}

__global__ void scan2_kernel(const int* __restrict__ bsums, int* __restrict__ bexc, int NB)
{
    __shared__ int tmp[256];
    int t = threadIdx.x;
    int v = (t < NB) ? bsums[t] : 0;
    tmp[t] = v;
    __syncthreads();
    for (int off = 1; off < 256; off <<= 1) {
        int add = (t >= off) ? tmp[t - off] : 0;
        __syncthreads();
        tmp[t] += add;
        __syncthreads();
    }
    bexc[t] = tmp[t] - v;
}

__global__ void scan3_kernel(int* __restrict__ starts, const int* __restrict__ bexc,
                             const int* __restrict__ counts, int* __restrict__ cursor, int N)
{
    int t = threadIdx.x;
    int i = blockIdx.x * 256 + t;
    if (i < N) {
        int val = starts[i] + bexc[blockIdx.x];
        starts[i] = val;
        cursor[i] = val;
        if (i == N - 1) starts[N] = val + counts[i];
    }
}

__global__ void scatter_kernel(const int* __restrict__ src, const int* __restrict__ dst,
                               int* __restrict__ cursor, int* __restrict__ csr_src, int E)
{
    int e = blockIdx.x * blockDim.x + threadIdx.x;
    if (e < E) {
        int d = dst[e];
        int slot = atomicAdd(&cursor[d], 1);
        csr_src[slot] = src[e];
    }
}

// ---------------------------------------------------------------------------
// Attention, bf16 QKV packed [M][768]. One wave/node; lane = (edge-slot, 8ch).
// One uint4 load serves 2 edges (16B/lane). No max-subtract (scores bounded;
// shift cancels exactly). 2 pair-slots in flight (4 edges/iter).
// ---------------------------------------------------------------------------
__global__ __launch_bounds__(256) void attn_kernel(
    const __hip_bfloat16* __restrict__ QKV,
    const int* __restrict__ starts, const int* __restrict__ csr_src,
    __hip_bfloat16* __restrict__ out)   // [M][256]
{
    const int n = blockIdx.x * 4 + (threadIdx.x >> 6);
    const int lane = threadIdx.x & 63;
    const int half = lane >> 5;          // which edge of the pair
    const int c = (lane & 31) << 3;      // 8-channel base
    const size_t qb = (size_t)n * 768;
    uint4 qv = *(const uint4*)(QKV + qb + c);
    float q[8]; unpack8(qv, q);
    const int beg = starts[n], end = starts[n + 1];
    const float SC = 0.17677669529663688f;   // 32^-0.5

    float l0 = 0.f, l1 = 0.f;
    float a0[8] = {0,0,0,0,0,0,0,0};
    float a1[8] = {0,0,0,0,0,0,0,0};
    for (int e = beg; e < end; e += 4) {
        int e0 = e + half, e1 = e + 2 + half;
        int s0 = csr_src[min(e0, end - 1)];
        int s1 = csr_src[min(e1, end - 1)];
        float m0 = (e0 < end) ? 1.f : 0.f;
        float m1 = (e1 < end) ? 1.f : 0.f;
        const __hip_bfloat16* p0 = QKV + (size_t)s0 * 768 + 256 + c;
        const __hip_bfloat16* p1 = QKV + (size_t)s1 * 768 + 256 + c;
        uint4 k0 = *(const uint4*)p0;
        uint4 k1 = *(const uint4*)p1;
        uint4 v0 = *(const uint4*)(p0 + 256);
        uint4 v1 = *(const uint4*)(p1 + 256);
        float kk[8], vv[8];
        unpack8(k0, kk);
        float d0 = q[0]*kk[0] + q[1]*kk[1] + q[2]*kk[2] + q[3]*kk[3]
                 + q[4]*kk[4] + q[5]*kk[5] + q[6]*kk[6] + q[7]*kk[7];
        unpack8(k1, kk);
        float d1 = q[0]*kk[0] + q[1]*kk[1] + q[2]*kk[2] + q[3]*kk[3]
                 + q[4]*kk[4] + q[5]*kk[5] + q[6]*kk[6] + q[7]*kk[7];
        d0 += __shfl_xor(d0, 1); d0 += __shfl_xor(d0, 2);
        d1 += __shfl_xor(d1, 1); d1 += __shfl_xor(d1, 2);
        float p0s = __expf(d0 * SC) * m0;
        float p1s = __expf(d1 * SC) * m1;
        l0 += p0s; l1 += p1s;
        unpack8(v0, vv);
        #pragma unroll
        for (int k = 0; k < 8; ++k) a0[k] += p0s * vv[k];
        unpack8(v1, vv);
        #pragma unroll
        for (int k = 0; k < 8; ++k) a1[k] += p1s * vv[k];
    }
    float l = l0 + l1;
    l += __shfl_xor(l, 32);
    float o[8];
    #pragma unroll
    for (int k = 0; k < 8; ++k) {
        float v = a0[k] + a1[k];
        v += __shfl_xor(v, 32);
        o[k] = v;
    }
    float inv = 1.f / (l + 1e-8f);
    #pragma unroll
    for (int k = 0; k < 8; ++k) o[k] *= inv;
    if (half == 0)
        *(uint4*)(out + (size_t)n * DIM + c) = pack8(o);
}

// ---------------------------------------------------------------------------
extern "C" void kernel_launch(void* const* d_in, const int* in_sizes, int n_in,
                              void* d_out, int out_size, void* d_ws, size_t ws_size,
                              hipStream_t stream)
{
    const float* x     = (const float*)d_in[0];
    const int*   edge  = (const int*)d_in[1];
    const float* Wq    = (const float*)d_in[3];
    const float* Wk    = (const float*)d_in[4];
    const float* Wv    = (const float*)d_in[5];
    const float* Wo_w  = (const float*)d_in[6];
    const float* Wo_b  = (const float*)d_in[7];
    const float* ln1_g = (const float*)d_in[8];
    const float* ln1_b = (const float*)d_in[9];
    const float* ln2_g = (const float*)d_in[10];
    const float* ln2_b = (const float*)d_in[11];
    const float* fw1   = (const float*)d_in[12];
    const float* fb1   = (const float*)d_in[13];
    const float* fw2   = (const float*)d_in[14];
    const float* fb2   = (const float*)d_in[15];
    const int* srcA = edge;
    const int* dstA = edge + NEDGES;

    char* p = (char*)d_ws;
    __hip_bfloat16* QKVh = (__hip_bfloat16*)p;  p += (size_t)NNODES * 768 * 2;
    __hip_bfloat16* AOh  = (__hip_bfloat16*)p;  p += (size_t)NNODES * DIM * 2;
    __hip_bfloat16* O1h  = (__hip_bfloat16*)p;  p += (size_t)NNODES * DIM * 2;
    __hip_bfloat16* HIDh = (__hip_bfloat16*)p;  p += (size_t)NNODES * HID_DIM * 2;
    __hip_bfloat16* xh   = (__hip_bfloat16*)p;  p += (size_t)NNODES * DIM * 2;
    unsigned short* WqkvT = (unsigned short*)p; p += (size_t)768 * 256 * 2;
    unsigned short* WoT   = (unsigned short*)p; p += (size_t)256 * 256 * 2;
    unsigned short* f1T   = (unsigned short*)p; p += (size_t)512 * 256 * 2;
    unsigned short* f2T   = (unsigned short*)p; p += (size_t)256 * 512 * 2;
    int* counts = (int*)p;  p += sizeof(int) * NNODES;
    int* starts = (int*)p;  p += sizeof(int) * (NNODES + 1);
    int* bsums  = (int*)p;  p += sizeof(int) * 256;
    int* bexc   = (int*)p;  p += sizeof(int) * 256;
    int* cursor = (int*)p;  p += sizeof(int) * NNODES;
    int* csr    = (int*)p;  p += sizeof(int) * NEDGES;

    const int NB = (NNODES + 255) / 256;
    const int mT = (NNODES + 63) / 64;        // 782 M-tiles
    dim3 blk(256);

    // conversions
    conv_bf16_kernel<<<(NNODES * DIM / 4 + 255) / 256, blk, 0, stream>>>(x, xh, NNODES * DIM / 4);
    prep_w_kernel<<<128, blk, 0, stream>>>(Wq, Wk, Wv, Wo_w, fw1, fw2, WqkvT, WoT, f1T, f2T);

    // CSR by dst
    hipMemsetAsync(counts, 0, sizeof(int) * NNODES, stream);
    hist_kernel<<<(NEDGES + 255) / 256, blk, 0, stream>>>(dstA, counts, NEDGES);
    scan1_kernel<<<NB, blk, 0, stream>>>(counts, starts, bsums, NNODES);
    scan2_kernel<<<1, blk, 0, stream>>>(bsums, bexc, NB);
    scan3_kernel<<<NB, blk, 0, stream>>>(starts, bexc, counts, cursor, NNODES);
    scatter_kernel<<<(NEDGES + 255) / 256, blk, 0, stream>>>(srcA, dstA, cursor, csr, NEDGES);

    // fused QKV projection: [M,256] @ [256,768]
    gemm_bf16_kernel<0><<<mT * 3, blk, 0, stream>>>(
        xh, (const __hip_bfloat16*)WqkvT, nullptr, nullptr, nullptr, nullptr,
        QKVh, nullptr, NNODES, 256, 768);

    // segmented attention
    attn_kernel<<<NNODES / 4, blk, 0, stream>>>(QKVh, starts, csr, AOh);

    // output projection + residual(x) + LN1 -> O1h (bf16)
    gemm_bf16_kernel<2><<<mT, blk, 0, stream>>>(
        AOh, (const __hip_bfloat16*)WoT, Wo_b, x, ln1_g, ln1_b,
        O1h, nullptr, NNODES, 256, 256);

    // FFN1 + GELU -> HIDh
    gemm_bf16_kernel<1><<<mT * 2, blk, 0, stream>>>(
        O1h, (const __hip_bfloat16*)f1T, fb1, nullptr, nullptr, nullptr,
        HIDh, nullptr, NNODES, 256, 512);

    // FFN2 + residual(O1h) + LN2 -> d_out (fp32)
    gemm_bf16_kernel<3><<<mT, blk, 0, stream>>>(
        HIDh, (const __hip_bfloat16*)f2T, fb2, O1h, ln2_g, ln2_b,
        nullptr, (float*)d_out, NNODES, 512, 256);
}